// Round 1
// baseline (585.261 us; speedup 1.0000x reference)
//
#include <hip/hip_runtime.h>
#include <stdint.h>

// LocalWindowAttention: B=2,T=4096,D=2048,H=16,HK=4,HD=128,WIN=512
// R3: (1) attn LDS XOR-swizzle (both-sides: pre-swizzled global src for
//     global_load_lds + swizzled ds_read / P-write) to kill the 16-way
//     bank conflict on Ks/Vs/P fragment reads (m214 G4 pattern, +89% there);
//     (2) XCD-chunked blockIdx swizzle on the GEMMs (T1) for A-panel L2 reuse.

typedef unsigned short u16;
typedef __attribute__((ext_vector_type(8))) short frag8;   // 8 bf16 = 4 VGPRs
typedef __attribute__((ext_vector_type(4))) float f32x4;   // MFMA acc

#define TILE 128

__device__ __forceinline__ u16 f2bf(float f) {
  union { float f; unsigned u; } c; c.f = f;
  unsigned u = c.u;
  return (u16)((u + 0x7fffu + ((u >> 16) & 1u)) >> 16);
}

// async global->LDS, 16B per lane; LDS dest = wave-uniform base + lane*16
__device__ __forceinline__ void async16(const u16* g, u16* l) {
  __builtin_amdgcn_global_load_lds((const __attribute__((address_space(1))) void*)g,
                                   (__attribute__((address_space(3))) void*)l, 16, 0, 0);
}

// T1: XCD-chunked remap. Requires gridDim.x % 8 == 0 (all our GEMM grids).
// XCD x owns bx in [x*gx/8, (x+1)*gx/8) for ALL by -> its 8 A-row-panels
// (8*128*2048*2B = 4MB) stay L2-resident across the by sweep.
__device__ __forceinline__ void xcd_map(int& bx, int& by) {
  const int gx = gridDim.x;
  const int cx = gx >> 3;
  int id = blockIdx.y * gx + blockIdx.x;
  int xcd = id & 7, local = id >> 3;
  bx = xcd * cx + (local % cx);
  by = local / cx;
}

// ---- m97-style 128x128 GEMM core: A [M,K] row-major bf16, Bt = B^T [N,K] row-major
__device__ __forceinline__ void gemm_core(const u16* __restrict__ A, int lda,
                                          const u16* __restrict__ Bt, int ldb,
                                          int K, u16* As, u16* Bs, f32x4 acc[4][4]) {
  const int tid = threadIdx.x;
  const int lane = tid & 63, wave = tid >> 6;
  const int wr = wave >> 1, wc = wave & 1;
  const int quad = lane >> 4, l16 = lane & 15;
#pragma unroll
  for (int i = 0; i < 4; ++i)
#pragma unroll
    for (int j = 0; j < 4; ++j) acc[i][j] = (f32x4){0.f, 0.f, 0.f, 0.f};

  const int row0 = tid >> 2, offc = (tid & 3) * 8;  // 128 rows x 32 k, 16B chunks
  for (int k0 = 0; k0 < K; k0 += 32) {
#pragma unroll
    for (int r = 0; r < 2; ++r) {
      int row = r * 64 + row0;
      async16(A + (long)row * lda + k0 + offc, As + r * 2048 + wave * 512);
      async16(Bt + (long)row * ldb + k0 + offc, Bs + r * 2048 + wave * 512);
    }
    __syncthreads();
    frag8 af[4], bf[4];
#pragma unroll
    for (int i = 0; i < 4; ++i)
      af[i] = *(const frag8*)(As + (wr * 64 + i * 16 + l16) * 32 + quad * 8);
#pragma unroll
    for (int j = 0; j < 4; ++j)
      bf[j] = *(const frag8*)(Bs + (wc * 64 + j * 16 + l16) * 32 + quad * 8);
#pragma unroll
    for (int i = 0; i < 4; ++i)
#pragma unroll
      for (int j = 0; j < 4; ++j)
        acc[i][j] = __builtin_amdgcn_mfma_f32_16x16x32_bf16(af[i], bf[j], acc[i][j], 0, 0, 0);
    __syncthreads();
  }
}

#define EPI_COORDS                                             \
  const int lane = threadIdx.x & 63, wave = threadIdx.x >> 6;  \
  const int wr = wave >> 1, wc = wave & 1;                     \
  const int quad = lane >> 4, l16 = lane & 15;

__global__ __launch_bounds__(256) void k_gemm_bf16(const u16* __restrict__ A, int lda,
                                                   const u16* __restrict__ Bt, int ldb,
                                                   u16* __restrict__ C, int ldc, int K) {
  __shared__ alignas(16) u16 smem[2 * TILE * 32];
  int bx, by; xcd_map(bx, by);
  f32x4 acc[4][4];
  gemm_core(A + (long)bx * TILE * lda, lda,
            Bt + (long)by * TILE * ldb, ldb, K, smem, smem + TILE * 32, acc);
  EPI_COORDS
  u16* Ct = C + (long)bx * TILE * ldc + (long)by * TILE;
#pragma unroll
  for (int i = 0; i < 4; ++i)
#pragma unroll
    for (int j = 0; j < 4; ++j) {
      int r0 = wr * 64 + i * 16 + quad * 4, cc = wc * 64 + j * 16 + l16;
#pragma unroll
      for (int r = 0; r < 4; ++r) Ct[(long)(r0 + r) * ldc + cc] = f2bf(acc[i][j][r]);
    }
}

// writes C^T: contiguous 4-element store per acc tile (for V^T layout)
__global__ __launch_bounds__(256) void k_gemm_bf16t(const u16* __restrict__ A, int lda,
                                                    const u16* __restrict__ Bt, int ldb,
                                                    u16* __restrict__ Ct, int ldct, int K) {
  __shared__ alignas(16) u16 smem[2 * TILE * 32];
  int bx, by; xcd_map(bx, by);
  f32x4 acc[4][4];
  gemm_core(A + (long)bx * TILE * lda, lda,
            Bt + (long)by * TILE * ldb, ldb, K, smem, smem + TILE * 32, acc);
  EPI_COORDS
  u16* Cb = Ct + (long)by * TILE * ldct + (long)bx * TILE;
#pragma unroll
  for (int i = 0; i < 4; ++i)
#pragma unroll
    for (int j = 0; j < 4; ++j) {
      int n = wc * 64 + j * 16 + l16, m0 = wr * 64 + i * 16 + quad * 4;
      ushort4 o;
      o.x = f2bf(acc[i][j][0]); o.y = f2bf(acc[i][j][1]);
      o.z = f2bf(acc[i][j][2]); o.w = f2bf(acc[i][j][3]);
      *(ushort4*)(Cb + (long)n * ldct + m0) = o;
    }
}

__global__ __launch_bounds__(256) void k_gemm_f32(const u16* __restrict__ A, int lda,
                                                  const u16* __restrict__ Bt, int ldb,
                                                  float* __restrict__ C, int ldc, int K) {
  __shared__ alignas(16) u16 smem[2 * TILE * 32];
  int bx, by; xcd_map(bx, by);
  f32x4 acc[4][4];
  gemm_core(A + (long)bx * TILE * lda, lda,
            Bt + (long)by * TILE * ldb, ldb, K, smem, smem + TILE * 32, acc);
  EPI_COORDS
  float* Ct = C + (long)bx * TILE * ldc + (long)by * TILE;
#pragma unroll
  for (int i = 0; i < 4; ++i)
#pragma unroll
    for (int j = 0; j < 4; ++j) {
      int r0 = wr * 64 + i * 16 + quad * 4, cc = wc * 64 + j * 16 + l16;
#pragma unroll
      for (int r = 0; r < 4; ++r) Ct[(long)(r0 + r) * ldc + cc] = acc[i][j][r];
    }
}

// ---- fused local-window attention --------------------------------------
// grid: x = qi (q 128-row block, 0..3), y = blk (0..7), z = b*16 + h (0..31)
// Each wave owns 32 query rows (2 row-tiles x 8 col-tiles). Online softmax
// state (m, l) per row lives in registers, replicated across each 16-lane group.
// Key window processed in 128-key chunks; chunk ci covers concat-window cols
// [ci*128, ci*128+128): ci<4 = prev block (skip if blk==0), ci>=4 = own block.
// Active chunks: ci in [qi, 4+qi]; ci==qi / ci==4+qi are the two diagonals.
//
// LDS swizzle (T2-analog, m214 G4): Ks/Vs rows are 256B -> naive fragment
// reads are 16-way bank-conflicted (all l16 lanes hit the same bank).
// Store data for (row, col16B) at col16B ^ (row&7) by pre-swizzling the
// GLOBAL source address (LDS dest of global_load_lds must stay linear),
// and XOR the same (row&7)<<3 (u16 units) into every ds_read / P ds_write.
__global__ __launch_bounds__(256, 2) void k_attn(const u16* __restrict__ qb,
                                                 const u16* __restrict__ kb,
                                                 const u16* __restrict__ vT,
                                                 u16* __restrict__ O) {
  __shared__ alignas(16) u16 Ks[128 * 128];  // [key][hd], swizzled; P overlays after S-phase
  __shared__ alignas(16) u16 Vs[128 * 128];  // [hd][key], swizzled
  const int tid = threadIdx.x, lane = tid & 63, wave = tid >> 6;
  const int quad = lane >> 4, l16 = lane & 15;
  const int qi = blockIdx.x, blk = blockIdx.y;
  const int b = blockIdx.z >> 4, h = blockIdx.z & 15, hk = h >> 2;
  const long tok_q = (long)b * 4096 + blk * 512 + qi * 128;
  const float scale = 0.08838834764831845f;  // 1/sqrt(128)

  // Q fragments for this wave's 32 rows, all of HD=128 (held across chunks)
  frag8 qf[2][4];
#pragma unroll
  for (int i = 0; i < 2; ++i)
#pragma unroll
    for (int kt = 0; kt < 4; ++kt)
      qf[i][kt] = *(const frag8*)(qb + (tok_q + wave * 32 + i * 16 + l16) * 2048 +
                                  h * 128 + kt * 32 + quad * 8);

  f32x4 o_acc[2][8];
  float m_r[2][4], l_r[2][4];
#pragma unroll
  for (int i = 0; i < 2; ++i) {
#pragma unroll
    for (int j = 0; j < 8; ++j) o_acc[i][j] = (f32x4){0.f, 0.f, 0.f, 0.f};
#pragma unroll
    for (int r = 0; r < 4; ++r) { m_r[i][r] = -1e30f; l_r[i][r] = 0.f; }
  }

  const int row_s = tid >> 4, off_s = (tid & 15) * 8;     // staging coords (128x128)
  const int sw_off = off_s ^ ((row_s & 7) << 3);          // pre-swizzled global col (u16)
  const int rsw = (l16 & 7) << 3;                         // read-side XOR (u16)
  u16* PsW = Ks + wave * 4096;                            // this wave's 32x128 P region

  for (int ci = (blk ? qi : 4); ci <= 4 + qi; ++ci) {
    const long tok_k = (long)b * 4096 + (blk - 1) * 512 + ci * 128;
    const int mode = (ci == qi) ? 1 : ((ci == 4 + qi) ? 2 : 0);  // 1: lk>rl, 2: lk<=rl

    // stage K chunk [128 key][128 hd] and V chunk [128 hd][128 key] (swizzled)
#pragma unroll
    for (int r2 = 0; r2 < 8; ++r2) {
      int row = r2 * 16 + row_s;
      async16(kb + (tok_k + row) * 512 + hk * 128 + sw_off, Ks + r2 * 2048 + wave * 512);
      async16(vT + ((long)hk * 128 + row) * 8192 + tok_k + sw_off, Vs + r2 * 2048 + wave * 512);
    }
    __syncthreads();

    // S = Q @ K^T  (32 rows x 128 keys per wave)
    f32x4 s_acc[2][8];
#pragma unroll
    for (int i = 0; i < 2; ++i)
#pragma unroll
      for (int j = 0; j < 8; ++j) s_acc[i][j] = (f32x4){0.f, 0.f, 0.f, 0.f};
#pragma unroll
    for (int kt = 0; kt < 4; ++kt) {
      frag8 bfr[8];
#pragma unroll
      for (int j = 0; j < 8; ++j)
        bfr[j] = *(const frag8*)(Ks + (j * 16 + l16) * 128 + ((kt * 32 + quad * 8) ^ rsw));
#pragma unroll
      for (int i = 0; i < 2; ++i)
#pragma unroll
        for (int j = 0; j < 8; ++j)
          s_acc[i][j] = __builtin_amdgcn_mfma_f32_16x16x32_bf16(qf[i][kt], bfr[j], s_acc[i][j], 0, 0, 0);
    }

    // scale + mask + per-row chunk max
    float mc[2][4];
#pragma unroll
    for (int i = 0; i < 2; ++i)
#pragma unroll
      for (int r = 0; r < 4; ++r) mc[i][r] = -1e30f;
#pragma unroll
    for (int i = 0; i < 2; ++i)
#pragma unroll
      for (int j = 0; j < 8; ++j)
#pragma unroll
        for (int r = 0; r < 4; ++r) {
          int rl = wave * 32 + i * 16 + quad * 4 + r;  // row within 128-q-block
          int lk = j * 16 + l16;                       // key within chunk
          bool ok = (mode == 0) || (mode == 1 ? (lk > rl) : (lk <= rl));
          float s = ok ? s_acc[i][j][r] * scale : -1e30f;
          s_acc[i][j][r] = s;
          mc[i][r] = fmaxf(mc[i][r], s);
        }
#pragma unroll
    for (int o = 1; o < 16; o <<= 1)
#pragma unroll
      for (int i = 0; i < 2; ++i)
#pragma unroll
        for (int r = 0; r < 4; ++r)
          mc[i][r] = fmaxf(mc[i][r], __shfl_xor(mc[i][r], o));

    // online-softmax update
    float alpha[2][4];
#pragma unroll
    for (int i = 0; i < 2; ++i)
#pragma unroll
      for (int r = 0; r < 4; ++r) {
        float mn = fmaxf(m_r[i][r], mc[i][r]);
        alpha[i][r] = __expf(m_r[i][r] - mn);  // m=-1e30 & mn=-1e30 -> exp(0)=1, l=0 anyway
        m_r[i][r] = mn;
        l_r[i][r] *= alpha[i][r];
      }
#pragma unroll
    for (int i = 0; i < 2; ++i)
#pragma unroll
      for (int j = 0; j < 8; ++j)
#pragma unroll
        for (int r = 0; r < 4; ++r) o_acc[i][j][r] *= alpha[i][r];

    float ps[2][4];
#pragma unroll
    for (int i = 0; i < 2; ++i)
#pragma unroll
      for (int r = 0; r < 4; ++r) ps[i][r] = 0.f;
#pragma unroll
    for (int i = 0; i < 2; ++i)
#pragma unroll
      for (int j = 0; j < 8; ++j)
#pragma unroll
        for (int r = 0; r < 4; ++r) {
          float s = s_acc[i][j][r];
          float e = __expf(s - m_r[i][r]);
          e = (s == -1e30f) ? 0.f : e;  // explicit mask gate (handles all-masked rows)
          s_acc[i][j][r] = e;
          ps[i][r] += e;
        }
#pragma unroll
    for (int o = 1; o < 16; o <<= 1)
#pragma unroll
      for (int i = 0; i < 2; ++i)
#pragma unroll
        for (int r = 0; r < 4; ++r) ps[i][r] += __shfl_xor(ps[i][r], o);
#pragma unroll
    for (int i = 0; i < 2; ++i)
#pragma unroll
      for (int r = 0; r < 4; ++r) l_r[i][r] += ps[i][r];

    __syncthreads();  // all waves done reading Ks before P overlays it

    // P: C-layout regs -> LDS [row][key] (wave-private region, same swizzle)
#pragma unroll
    for (int i = 0; i < 2; ++i)
#pragma unroll
      for (int r = 0; r < 4; ++r) {
        int xw = ((quad * 4 + r) & 7) << 3;  // rowP&7 == (quad*4+r)&7
#pragma unroll
        for (int j = 0; j < 8; ++j)
          PsW[(i * 16 + quad * 4 + r) * 128 + ((j * 16 + l16) ^ xw)] = f2bf(s_acc[i][j][r]);
      }

    // O += P @ V
#pragma unroll
    for (int kt = 0; kt < 4; ++kt) {
      frag8 pf[2], vf[8];
#pragma unroll
      for (int i = 0; i < 2; ++i)
        pf[i] = *(const frag8*)(PsW + (i * 16 + l16) * 128 + ((kt * 32 + quad * 8) ^ rsw));
#pragma unroll
      for (int j = 0; j < 8; ++j)
        vf[j] = *(const frag8*)(Vs + (j * 16 + l16) * 128 + ((kt * 32 + quad * 8) ^ rsw));
#pragma unroll
      for (int i = 0; i < 2; ++i)
#pragma unroll
        for (int j = 0; j < 8; ++j)
          o_acc[i][j] = __builtin_amdgcn_mfma_f32_16x16x32_bf16(pf[i], vf[j], o_acc[i][j], 0, 0, 0);
    }
    __syncthreads();  // before next chunk's staging overwrites Ks/Vs
  }

  // epilogue: O / l
  float inv[2][4];
#pragma unroll
  for (int i = 0; i < 2; ++i)
#pragma unroll
    for (int r = 0; r < 4; ++r) inv[i][r] = 1.0f / l_r[i][r];
#pragma unroll
  for (int i = 0; i < 2; ++i)
#pragma unroll
    for (int j = 0; j < 8; ++j)
#pragma unroll
      for (int r = 0; r < 4; ++r) {
        long row = tok_q + wave * 32 + i * 16 + quad * 4 + r;
        O[row * 2048 + h * 128 + j * 16 + l16] = f2bf(o_acc[i][j][r] * inv[i][r]);
      }
}

__global__ void k_convert(const float4* __restrict__ x, ushort4* __restrict__ xb) {
  int i = blockIdx.x * 256 + threadIdx.x;
  float4 f = x[i];
  ushort4 o;
  o.x = f2bf(f.x); o.y = f2bf(f.y); o.z = f2bf(f.z); o.w = f2bf(f.w);
  xb[i] = o;
}

// W [K,N] fp32 -> W^T [N,K] bf16
__global__ void k_transpose(const float* __restrict__ W, u16* __restrict__ WT, int K, int N) {
  __shared__ float sh[32][33];
  int n0 = blockIdx.x * 32, k0 = blockIdx.y * 32;
  int tx = threadIdx.x, ty = threadIdx.y;  // (32, 8)
#pragma unroll
  for (int i = 0; i < 32; i += 8) sh[ty + i][tx] = W[(long)(k0 + ty + i) * N + n0 + tx];
  __syncthreads();
#pragma unroll
  for (int i = 0; i < 32; i += 8) WT[(long)(n0 + ty + i) * K + k0 + tx] = f2bf(sh[tx][ty + i]);
}

extern "C" void kernel_launch(void* const* d_in, const int* in_sizes, int n_in,
                              void* d_out, int out_size, void* d_ws, size_t ws_size,
                              hipStream_t stream) {
  const float* x  = (const float*)d_in[0];
  const float* Wq = (const float*)d_in[1];
  const float* Wk = (const float*)d_in[2];
  const float* Wv = (const float*)d_in[3];
  const float* Wo = (const float*)d_in[4];
  float* out = (float*)d_out;

  const long BT = 8192, D = 2048, NKV = 512;
  size_t off = 0;
  auto alloc = [&](size_t bytes) -> char* {
    off = (off + 255) & ~(size_t)255;
    char* p = (char*)d_ws + off;
    off += bytes;
    return p;
  };

  u16* xb  = (u16*)alloc((size_t)BT * D * 2);  // reused as attention output
  u16* WqT = (u16*)alloc((size_t)D * D * 2);
  u16* WkT = (u16*)alloc((size_t)NKV * D * 2);
  u16* WvT = (u16*)alloc((size_t)NKV * D * 2);
  u16* WoT = (u16*)alloc((size_t)D * D * 2);
  u16* qb  = (u16*)alloc((size_t)BT * D * 2);
  u16* kb  = (u16*)alloc((size_t)BT * NKV * 2);
  u16* vT  = (u16*)alloc((size_t)NKV * BT * 2);
  u16* Oa  = xb;

  k_convert<<<16384, 256, 0, stream>>>((const float4*)x, (ushort4*)xb);
  dim3 tb(32, 8);
  k_transpose<<<dim3(64, 64), tb, 0, stream>>>(Wq, WqT, 2048, 2048);
  k_transpose<<<dim3(16, 64), tb, 0, stream>>>(Wk, WkT, 2048, 512);
  k_transpose<<<dim3(16, 64), tb, 0, stream>>>(Wv, WvT, 2048, 512);
  k_transpose<<<dim3(64, 64), tb, 0, stream>>>(Wo, WoT, 2048, 2048);

  k_gemm_bf16 <<<dim3(64, 16), 256, 0, stream>>>(xb, 2048, WqT, 2048, qb, 2048, 2048);
  k_gemm_bf16 <<<dim3(64, 4),  256, 0, stream>>>(xb, 2048, WkT, 2048, kb, 512, 2048);
  k_gemm_bf16t<<<dim3(64, 4),  256, 0, stream>>>(xb, 2048, WvT, 2048, vT, 8192, 2048);

  k_attn<<<dim3(4, 8, 32), 256, 0, stream>>>(qb, kb, vT, Oa);

  k_gemm_f32<<<dim3(64, 16), 256, 0, stream>>>(Oa, 2048, WoT, 2048, out, 2048, 2048);
}

// Round 2
// 545.696 us; speedup vs baseline: 1.0725x; 1.0725x over previous
//
#include <hip/hip_runtime.h>
#include <stdint.h>

// LocalWindowAttention: B=2,T=4096,D=2048,H=16,HK=4,HD=128,WIN=512
// R4: attn overhaul — (1) 64-key chunks double-buffered with issue-early
//     prefetch (T3 minimum 2-phase): stage(next) before S+softmax, mid
//     __syncthreads drains; (2) XCD co-location: 16 sibling blocks sharing a
//     (b,hk,blk) K/V window get consecutive ids with constant id%8 and id/128
//     -> same XCD L2 (kills the 8.6x K/V HBM re-fetch); (3) LDS-bounce O
//     epilogue for coalesced 16B stores (3x write amplification fix).
//     GEMMs unchanged from R3 (xcd_map kept).

typedef unsigned short u16;
typedef __attribute__((ext_vector_type(8))) short frag8;   // 8 bf16 = 4 VGPRs
typedef __attribute__((ext_vector_type(4))) float f32x4;   // MFMA acc

#define TILE 128

__device__ __forceinline__ u16 f2bf(float f) {
  union { float f; unsigned u; } c; c.f = f;
  unsigned u = c.u;
  return (u16)((u + 0x7fffu + ((u >> 16) & 1u)) >> 16);
}

// async global->LDS, 16B per lane; LDS dest = wave-uniform base + lane*16
__device__ __forceinline__ void async16(const u16* g, u16* l) {
  __builtin_amdgcn_global_load_lds((const __attribute__((address_space(1))) void*)g,
                                   (__attribute__((address_space(3))) void*)l, 16, 0, 0);
}

// T1: XCD-chunked remap. Requires gridDim.x % 8 == 0 (all our GEMM grids).
__device__ __forceinline__ void xcd_map(int& bx, int& by) {
  const int gx = gridDim.x;
  const int cx = gx >> 3;
  int id = blockIdx.y * gx + blockIdx.x;
  int xcd = id & 7, local = id >> 3;
  bx = xcd * cx + (local % cx);
  by = local / cx;
}

// ---- m97-style 128x128 GEMM core: A [M,K] row-major bf16, Bt = B^T [N,K] row-major
__device__ __forceinline__ void gemm_core(const u16* __restrict__ A, int lda,
                                          const u16* __restrict__ Bt, int ldb,
                                          int K, u16* As, u16* Bs, f32x4 acc[4][4]) {
  const int tid = threadIdx.x;
  const int lane = tid & 63, wave = tid >> 6;
  const int wr = wave >> 1, wc = wave & 1;
  const int quad = lane >> 4, l16 = lane & 15;
#pragma unroll
  for (int i = 0; i < 4; ++i)
#pragma unroll
    for (int j = 0; j < 4; ++j) acc[i][j] = (f32x4){0.f, 0.f, 0.f, 0.f};

  const int row0 = tid >> 2, offc = (tid & 3) * 8;  // 128 rows x 32 k, 16B chunks
  for (int k0 = 0; k0 < K; k0 += 32) {
#pragma unroll
    for (int r = 0; r < 2; ++r) {
      int row = r * 64 + row0;
      async16(A + (long)row * lda + k0 + offc, As + r * 2048 + wave * 512);
      async16(Bt + (long)row * ldb + k0 + offc, Bs + r * 2048 + wave * 512);
    }
    __syncthreads();
    frag8 af[4], bf[4];
#pragma unroll
    for (int i = 0; i < 4; ++i)
      af[i] = *(const frag8*)(As + (wr * 64 + i * 16 + l16) * 32 + quad * 8);
#pragma unroll
    for (int j = 0; j < 4; ++j)
      bf[j] = *(const frag8*)(Bs + (wc * 64 + j * 16 + l16) * 32 + quad * 8);
#pragma unroll
    for (int i = 0; i < 4; ++i)
#pragma unroll
      for (int j = 0; j < 4; ++j)
        acc[i][j] = __builtin_amdgcn_mfma_f32_16x16x32_bf16(af[i], bf[j], acc[i][j], 0, 0, 0);
    __syncthreads();
  }
}

#define EPI_COORDS                                             \
  const int lane = threadIdx.x & 63, wave = threadIdx.x >> 6;  \
  const int wr = wave >> 1, wc = wave & 1;                     \
  const int quad = lane >> 4, l16 = lane & 15;

__global__ __launch_bounds__(256) void k_gemm_bf16(const u16* __restrict__ A, int lda,
                                                   const u16* __restrict__ Bt, int ldb,
                                                   u16* __restrict__ C, int ldc, int K) {
  __shared__ alignas(16) u16 smem[2 * TILE * 32];
  int bx, by; xcd_map(bx, by);
  f32x4 acc[4][4];
  gemm_core(A + (long)bx * TILE * lda, lda,
            Bt + (long)by * TILE * ldb, ldb, K, smem, smem + TILE * 32, acc);
  EPI_COORDS
  u16* Ct = C + (long)bx * TILE * ldc + (long)by * TILE;
#pragma unroll
  for (int i = 0; i < 4; ++i)
#pragma unroll
    for (int j = 0; j < 4; ++j) {
      int r0 = wr * 64 + i * 16 + quad * 4, cc = wc * 64 + j * 16 + l16;
#pragma unroll
      for (int r = 0; r < 4; ++r) Ct[(long)(r0 + r) * ldc + cc] = f2bf(acc[i][j][r]);
    }
}

// writes C^T: contiguous 4-element store per acc tile (for V^T layout)
__global__ __launch_bounds__(256) void k_gemm_bf16t(const u16* __restrict__ A, int lda,
                                                    const u16* __restrict__ Bt, int ldb,
                                                    u16* __restrict__ Ct, int ldct, int K) {
  __shared__ alignas(16) u16 smem[2 * TILE * 32];
  int bx, by; xcd_map(bx, by);
  f32x4 acc[4][4];
  gemm_core(A + (long)bx * TILE * lda, lda,
            Bt + (long)by * TILE * ldb, ldb, K, smem, smem + TILE * 32, acc);
  EPI_COORDS
  u16* Cb = Ct + (long)by * TILE * ldct + (long)bx * TILE;
#pragma unroll
  for (int i = 0; i < 4; ++i)
#pragma unroll
    for (int j = 0; j < 4; ++j) {
      int n = wc * 64 + j * 16 + l16, m0 = wr * 64 + i * 16 + quad * 4;
      ushort4 o;
      o.x = f2bf(acc[i][j][0]); o.y = f2bf(acc[i][j][1]);
      o.z = f2bf(acc[i][j][2]); o.w = f2bf(acc[i][j][3]);
      *(ushort4*)(Cb + (long)n * ldct + m0) = o;
    }
}

__global__ __launch_bounds__(256) void k_gemm_f32(const u16* __restrict__ A, int lda,
                                                  const u16* __restrict__ Bt, int ldb,
                                                  float* __restrict__ C, int ldc, int K) {
  __shared__ alignas(16) u16 smem[2 * TILE * 32];
  int bx, by; xcd_map(bx, by);
  f32x4 acc[4][4];
  gemm_core(A + (long)bx * TILE * lda, lda,
            Bt + (long)by * TILE * ldb, ldb, K, smem, smem + TILE * 32, acc);
  EPI_COORDS
  float* Ct = C + (long)bx * TILE * ldc + (long)by * TILE;
#pragma unroll
  for (int i = 0; i < 4; ++i)
#pragma unroll
    for (int j = 0; j < 4; ++j) {
      int r0 = wr * 64 + i * 16 + quad * 4, cc = wc * 64 + j * 16 + l16;
#pragma unroll
      for (int r = 0; r < 4; ++r) Ct[(long)(r0 + r) * ldc + cc] = acc[i][j][r];
    }
}

// ---- fused local-window attention --------------------------------------
// 1024 blocks; work decoded from linear id so that the 16 blocks of a
// (b,hk,blk) group (4 h x 4 qi, sharing one K/V window) occupy 16
// consecutive ids with constant id%8 AND constant id/128 -> same XCD under
// either round-robin or chunked dispatch->XCD mapping.
//
// Key window processed in 64-key chunks ci (64 units): prev block = ci<8,
// own block = ci>=8. Active: ci in [2*qi, 9+2*qi] (blk>0) or [8, 9+2*qi]
// (blk==0). Mask is two affine tests (interior chunks trivially pass).
// K/V double-buffered (4x16KB = 64KB LDS); next chunk's global_load_lds
// issued BEFORE S-phase, drained by the mid __syncthreads -> staging
// overlaps S+softmax (T3 minimum 2-phase).
//
// LDS swizzle: store (row, col ^ ((row&7)<<3)) via pre-swizzled GLOBAL src
// (LDS dest of global_load_lds stays linear); same XOR on ds_read / P-write.
__global__ __launch_bounds__(256, 2) void k_attn(const u16* __restrict__ qb,
                                                 const u16* __restrict__ kb,
                                                 const u16* __restrict__ vT,
                                                 u16* __restrict__ O) {
  __shared__ alignas(16) u16 Ks[2][64 * 128];  // [key][hd]; P overlays cur after S
  __shared__ alignas(16) u16 Vs[2][128 * 64];  // [hd][key]
  const int tid = threadIdx.x, lane = tid & 63, wave = tid >> 6;
  const int quad = lane >> 4, l16 = lane & 15;

  // XCD-group decode
  const int id = blockIdx.x + 4 * blockIdx.y + 32 * blockIdx.z;  // 0..1023
  const int g = (id & 7) | ((id >> 7) << 3);                     // group 0..63
  const int w = (id >> 3) & 15;                                  // member 0..15
  const int hk = g & 3, blk = (g >> 2) & 7, b = g >> 5;
  const int h = hk * 4 + (w & 3), qi = w >> 2;

  const long tok_q = (long)b * 4096 + blk * 512 + qi * 128;
  const float scale = 0.08838834764831845f;  // 1/sqrt(128)

  // Q fragments for this wave's 32 rows, all of HD=128 (held across chunks)
  frag8 qf[2][4];
#pragma unroll
  for (int i = 0; i < 2; ++i)
#pragma unroll
    for (int kt = 0; kt < 4; ++kt)
      qf[i][kt] = *(const frag8*)(qb + (tok_q + wave * 32 + i * 16 + l16) * 2048 +
                                  h * 128 + kt * 32 + quad * 8);

  f32x4 o_acc[2][8];
  float m_r[2][4], l_r[2][4];
#pragma unroll
  for (int i = 0; i < 2; ++i) {
#pragma unroll
    for (int j = 0; j < 8; ++j) o_acc[i][j] = (f32x4){0.f, 0.f, 0.f, 0.f};
#pragma unroll
    for (int r = 0; r < 4; ++r) { m_r[i][r] = -1e30f; l_r[i][r] = 0.f; }
  }

  const int rsw = (l16 & 7) << 3;  // read-side XOR (u16)

  // stage one 64-key chunk: K [64 key][128 hd], V [128 hd][64 key], swizzled
  auto stage = [&](int buf, int ci) {
    const long tk = (long)b * 4096 + (blk - 1) * 512 + ci * 64;
#pragma unroll
    for (int c = 0; c < 4; ++c) {
      const int idx = (wave * 4 + c) * 512 + lane * 8;  // u16 index, linear
      {  // K: row = idx/128, col = idx%128
        int row = idx >> 7, col = idx & 127;
        async16(kb + (tk + row) * 512 + hk * 128 + (col ^ ((row & 7) << 3)),
                &Ks[buf][(wave * 4 + c) * 512]);
      }
      {  // V: row = idx/64, col = idx%64
        int row = idx >> 6, col = idx & 63;
        async16(vT + ((long)hk * 128 + row) * 8192 + tk + (col ^ ((row & 7) << 3)),
                &Vs[buf][(wave * 4 + c) * 512]);
      }
    }
  };

  const int c0 = blk ? 2 * qi : 8, c1 = 9 + 2 * qi;
  int cur = 0;
  stage(0, c0);
  __syncthreads();  // drain prologue staging

  for (int ci = c0; ci <= c1; ++ci) {
    if (ci < c1) stage(cur ^ 1, ci + 1);  // issue-early prefetch (overlaps S+softmax)

    // S = Q @ K^T  (32 rows x 64 keys per wave)
    f32x4 s_acc[2][4];
#pragma unroll
    for (int i = 0; i < 2; ++i)
#pragma unroll
      for (int j = 0; j < 4; ++j) s_acc[i][j] = (f32x4){0.f, 0.f, 0.f, 0.f};
#pragma unroll
    for (int kt = 0; kt < 4; ++kt) {
      frag8 bfr[4];
#pragma unroll
      for (int j = 0; j < 4; ++j)
        bfr[j] = *(const frag8*)(&Ks[cur][(j * 16 + l16) * 128 + ((kt * 32 + quad * 8) ^ rsw)]);
#pragma unroll
      for (int i = 0; i < 2; ++i)
#pragma unroll
        for (int j = 0; j < 4; ++j)
          s_acc[i][j] = __builtin_amdgcn_mfma_f32_16x16x32_bf16(qf[i][kt], bfr[j], s_acc[i][j], 0, 0, 0);
    }

    // scale + mask (two affine tests; interior chunks trivially pass) + chunk max
    const bool prev = (ci < 8);
    const int doff = (prev ? ci * 64 : (ci - 8) * 64) - qi * 128;
    float mc[2][4];
#pragma unroll
    for (int i = 0; i < 2; ++i)
#pragma unroll
      for (int r = 0; r < 4; ++r) mc[i][r] = -1e30f;
#pragma unroll
    for (int i = 0; i < 2; ++i)
#pragma unroll
      for (int j = 0; j < 4; ++j)
#pragma unroll
        for (int r = 0; r < 4; ++r) {
          int rl = wave * 32 + i * 16 + quad * 4 + r;  // row within 128-q-block
          int lk = j * 16 + l16;                       // key within chunk
          bool ok = prev ? (lk + doff > rl) : (lk + doff <= rl);
          float s = ok ? s_acc[i][j][r] * scale : -1e30f;
          s_acc[i][j][r] = s;
          mc[i][r] = fmaxf(mc[i][r], s);
        }
#pragma unroll
    for (int o = 1; o < 16; o <<= 1)
#pragma unroll
      for (int i = 0; i < 2; ++i)
#pragma unroll
        for (int r = 0; r < 4; ++r)
          mc[i][r] = fmaxf(mc[i][r], __shfl_xor(mc[i][r], o));

    // online-softmax update
    float alpha[2][4];
#pragma unroll
    for (int i = 0; i < 2; ++i)
#pragma unroll
      for (int r = 0; r < 4; ++r) {
        float mn = fmaxf(m_r[i][r], mc[i][r]);
        alpha[i][r] = __expf(m_r[i][r] - mn);
        m_r[i][r] = mn;
        l_r[i][r] *= alpha[i][r];
      }
#pragma unroll
    for (int i = 0; i < 2; ++i)
#pragma unroll
      for (int j = 0; j < 8; ++j)
#pragma unroll
        for (int r = 0; r < 4; ++r) o_acc[i][j][r] *= alpha[i][r];

    float ps[2][4];
#pragma unroll
    for (int i = 0; i < 2; ++i)
#pragma unroll
      for (int r = 0; r < 4; ++r) ps[i][r] = 0.f;
#pragma unroll
    for (int i = 0; i < 2; ++i)
#pragma unroll
      for (int j = 0; j < 4; ++j)
#pragma unroll
        for (int r = 0; r < 4; ++r) {
          float s = s_acc[i][j][r];
          float e = __expf(s - m_r[i][r]);
          e = (s == -1e30f) ? 0.f : e;  // mask gate (handles all-masked rows)
          s_acc[i][j][r] = e;
          ps[i][r] += e;
        }
#pragma unroll
    for (int o = 1; o < 16; o <<= 1)
#pragma unroll
      for (int i = 0; i < 2; ++i)
#pragma unroll
        for (int r = 0; r < 4; ++r) ps[i][r] += __shfl_xor(ps[i][r], o);
#pragma unroll
    for (int i = 0; i < 2; ++i)
#pragma unroll
      for (int r = 0; r < 4; ++r) l_r[i][r] += ps[i][r];

    __syncthreads();  // (a) all Ks[cur] reads done -> P may overlay
                      // (b) drains prefetch vmcnt -> next chunk staged

    // P: C-layout regs -> Ks[cur] overlay [32 row][64 key] per wave, swizzled
    u16* PsW = &Ks[cur][wave * 2048];
#pragma unroll
    for (int i = 0; i < 2; ++i)
#pragma unroll
      for (int r = 0; r < 4; ++r) {
        int xw = ((quad * 4 + r) & 7) << 3;  // row&7 == (quad*4+r)&7
#pragma unroll
        for (int j = 0; j < 4; ++j)
          PsW[(i * 16 + quad * 4 + r) * 64 + ((j * 16 + l16) ^ xw)] = f2bf(s_acc[i][j][r]);
      }

    // O += P @ V
#pragma unroll
    for (int kt = 0; kt < 2; ++kt) {
      frag8 pf[2], vf[8];
#pragma unroll
      for (int i = 0; i < 2; ++i)
        pf[i] = *(const frag8*)(PsW + (i * 16 + l16) * 64 + ((kt * 32 + quad * 8) ^ rsw));
#pragma unroll
      for (int j = 0; j < 8; ++j)
        vf[j] = *(const frag8*)(&Vs[cur][(j * 16 + l16) * 64 + ((kt * 32 + quad * 8) ^ rsw)]);
#pragma unroll
      for (int i = 0; i < 2; ++i)
#pragma unroll
        for (int j = 0; j < 8; ++j)
          o_acc[i][j] = __builtin_amdgcn_mfma_f32_16x16x32_bf16(pf[i], vf[j], o_acc[i][j], 0, 0, 0);
    }
    __syncthreads();  // all waves done with Ks[cur]/Vs[cur] before restage
    cur ^= 1;
  }

  // epilogue: O/l via LDS bounce -> coalesced 16B row-contiguous stores
  float inv[2][4];
#pragma unroll
  for (int i = 0; i < 2; ++i)
#pragma unroll
    for (int r = 0; r < 4; ++r) inv[i][r] = 1.0f / l_r[i][r];
  u16* Ob = &Ks[0][0];  // 32KB contiguous: [128 row][128 u16]
#pragma unroll
  for (int i = 0; i < 2; ++i)
#pragma unroll
    for (int j = 0; j < 8; ++j)
#pragma unroll
      for (int r = 0; r < 4; ++r)
        Ob[(wave * 32 + i * 16 + quad * 4 + r) * 128 + j * 16 + l16] =
            f2bf(o_acc[i][j][r] * inv[i][r]);
  __syncthreads();
#pragma unroll
  for (int p = 0; p < 8; ++p) {
    int idx = p * 256 + tid;
    int row = idx >> 4, col = (idx & 15) * 8;
    *(frag8*)(O + (tok_q + row) * 2048 + h * 128 + col) = *(const frag8*)(Ob + row * 128 + col);
  }
}

__global__ void k_convert(const float4* __restrict__ x, ushort4* __restrict__ xb) {
  int i = blockIdx.x * 256 + threadIdx.x;
  float4 f = x[i];
  ushort4 o;
  o.x = f2bf(f.x); o.y = f2bf(f.y); o.z = f2bf(f.z); o.w = f2bf(f.w);
  xb[i] = o;
}

// W [K,N] fp32 -> W^T [N,K] bf16
__global__ void k_transpose(const float* __restrict__ W, u16* __restrict__ WT, int K, int N) {
  __shared__ float sh[32][33];
  int n0 = blockIdx.x * 32, k0 = blockIdx.y * 32;
  int tx = threadIdx.x, ty = threadIdx.y;  // (32, 8)
#pragma unroll
  for (int i = 0; i < 32; i += 8) sh[ty + i][tx] = W[(long)(k0 + ty + i) * N + n0 + tx];
  __syncthreads();
#pragma unroll
  for (int i = 0; i < 32; i += 8) WT[(long)(n0 + ty + i) * K + k0 + tx] = f2bf(sh[tx][ty + i]);
}

extern "C" void kernel_launch(void* const* d_in, const int* in_sizes, int n_in,
                              void* d_out, int out_size, void* d_ws, size_t ws_size,
                              hipStream_t stream) {
  const float* x  = (const float*)d_in[0];
  const float* Wq = (const float*)d_in[1];
  const float* Wk = (const float*)d_in[2];
  const float* Wv = (const float*)d_in[3];
  const float* Wo = (const float*)d_in[4];
  float* out = (float*)d_out;

  const long BT = 8192, D = 2048, NKV = 512;
  size_t off = 0;
  auto alloc = [&](size_t bytes) -> char* {
    off = (off + 255) & ~(size_t)255;
    char* p = (char*)d_ws + off;
    off += bytes;
    return p;
  };

  u16* xb  = (u16*)alloc((size_t)BT * D * 2);  // reused as attention output
  u16* WqT = (u16*)alloc((size_t)D * D * 2);
  u16* WkT = (u16*)alloc((size_t)NKV * D * 2);
  u16* WvT = (u16*)alloc((size_t)NKV * D * 2);
  u16* WoT = (u16*)alloc((size_t)D * D * 2);
  u16* qb  = (u16*)alloc((size_t)BT * D * 2);
  u16* kb  = (u16*)alloc((size_t)BT * NKV * 2);
  u16* vT  = (u16*)alloc((size_t)NKV * BT * 2);
  u16* Oa  = xb;

  k_convert<<<16384, 256, 0, stream>>>((const float4*)x, (ushort4*)xb);
  dim3 tb(32, 8);
  k_transpose<<<dim3(64, 64), tb, 0, stream>>>(Wq, WqT, 2048, 2048);
  k_transpose<<<dim3(16, 64), tb, 0, stream>>>(Wk, WkT, 2048, 512);
  k_transpose<<<dim3(16, 64), tb, 0, stream>>>(Wv, WvT, 2048, 512);
  k_transpose<<<dim3(64, 64), tb, 0, stream>>>(Wo, WoT, 2048, 2048);

  k_gemm_bf16 <<<dim3(64, 16), 256, 0, stream>>>(xb, 2048, WqT, 2048, qb, 2048, 2048);
  k_gemm_bf16 <<<dim3(64, 4),  256, 0, stream>>>(xb, 2048, WkT, 2048, kb, 512, 2048);
  k_gemm_bf16t<<<dim3(64, 4),  256, 0, stream>>>(xb, 2048, WvT, 2048, vT, 8192, 2048);

  k_attn<<<dim3(4, 8, 32), 256, 0, stream>>>(qb, kb, vT, Oa);

  k_gemm_f32<<<dim3(64, 16), 256, 0, stream>>>(Oa, 2048, WoT, 2048, out, 2048, 2048);
}

// Round 3
// 519.405 us; speedup vs baseline: 1.1268x; 1.0506x over previous
//
#include <hip/hip_runtime.h>
#include <stdint.h>

// LocalWindowAttention: B=2,T=4096,D=2048,H=16,HK=4,HD=128,WIN=512
// R5: 256x256-tile 4-phase deep-pipelined GEMM (k_gemm256) for the two big
//     projections (Q, Wo): 512 thr / 8 waves (2Mx4N), BK=64, 128KB dbuf LDS,
//     raw s_barrier + counted vmcnt(2) (never 0 in steady state), XOR LDS
//     swizzle via pre-swizzled global src (rule #21), setprio around MFMA
//     clusters (T5). K/V projections (N=512) stay on the 128^2 kernel.
//     attn unchanged from R4.

typedef unsigned short u16;
typedef __attribute__((ext_vector_type(8))) short frag8;   // 8 bf16 = 4 VGPRs
typedef __attribute__((ext_vector_type(4))) float f32x4;   // MFMA acc

#define TILE 128

__device__ __forceinline__ u16 f2bf(float f) {
  union { float f; unsigned u; } c; c.f = f;
  unsigned u = c.u;
  return (u16)((u + 0x7fffu + ((u >> 16) & 1u)) >> 16);
}

// async global->LDS, 16B per lane; LDS dest = wave-uniform base + lane*16
__device__ __forceinline__ void async16(const u16* g, u16* l) {
  __builtin_amdgcn_global_load_lds((const __attribute__((address_space(1))) void*)g,
                                   (__attribute__((address_space(3))) void*)l, 16, 0, 0);
}

// T1: XCD-chunked remap. Requires gridDim.x % 8 == 0.
__device__ __forceinline__ void xcd_map(int& bx, int& by) {
  const int gx = gridDim.x;
  const int cx = gx >> 3;
  int id = blockIdx.y * gx + blockIdx.x;
  int xcd = id & 7, local = id >> 3;
  bx = xcd * cx + (local % cx);
  by = local / cx;
}

// ======================= 256^2 4-phase GEMM ==============================
// A [M,K] row-major bf16, Bt = B^T [N,K] row-major bf16, C [M,N] (u16|f32).
// Tile 256x256, BK=64, nt = K/64 K-tiles, double-buffered.
// LDS layout per tile: [256 rows][64 k] bf16 with col ^= (row&7)<<3 swizzle
// (u16 units). Staged linearly by global_load_lds with INVERSE-swizzled
// global source: issue c, wave w, lane l -> row = c*64+w*8+(l>>3),
// src col = ((l&7)^(l>>3))*8  (row&7 == l>>3, so involution holds).
// Per K-tile: 4 phases (Mhalf x Nhalf quadrants), 16 MFMA each; 2 stage
// issues per phase (A halves at P0/P1, B halves at P2/P3) -> 8 inst/tile.
// Tile-boundary wait: vmcnt(2) (the 2 newest = next tile's A c0,c1).
template <typename OutT>
__global__ __launch_bounds__(512, 2) void k_gemm256(const u16* __restrict__ A, int lda,
                                                    const u16* __restrict__ Bt, int ldb,
                                                    OutT* __restrict__ C, int ldc, int K) {
  __shared__ alignas(16) u16 Ab[2][256 * 64];  // 64 KB
  __shared__ alignas(16) u16 Bb[2][256 * 64];  // 64 KB
  const int tid = threadIdx.x, lane = tid & 63, wave = tid >> 6;
  const int wm = wave >> 2, wn = wave & 3;     // 2M x 4N wave grid
  const int quad = lane >> 4, l16 = lane & 15;

  int bx, by;
  xcd_map(bx, by);

  // staging coords (per-thread invariant)
  const int rsub = wave * 8 + (lane >> 3);                 // 0..63 within 64-row group
  const int csub = ((lane & 7) ^ (lane >> 3)) * 8;         // inverse-swizzled k col
  const u16* Ag = A + ((long)bx * 256 + rsub) * lda + csub;
  const u16* Bg = Bt + ((long)by * 256 + rsub) * ldb + csub;
  const long a64 = (long)64 * lda, b64 = (long)64 * ldb;

  const int rsw = (l16 & 7) << 3;  // read-side XOR (u16 units)

  f32x4 acc[8][4];
#pragma unroll
  for (int i = 0; i < 8; ++i)
#pragma unroll
    for (int j = 0; j < 4; ++j) acc[i][j] = (f32x4){0.f, 0.f, 0.f, 0.f};

  const int nt = K >> 6;

  // prologue: stage tile 0 (8 inst/wave)
#pragma unroll
  for (int c = 0; c < 4; ++c) {
    async16(Ag + c * a64, &Ab[0][c * 4096 + wave * 512]);
    async16(Bg + c * b64, &Bb[0][c * 4096 + wave * 512]);
  }

  for (int t = 0; t < nt; ++t) {
    const int buf = t & 1, nb = buf ^ 1;
    const long koff = (long)(t + 1) << 6;
    const bool hn = (t + 1 < nt);
    frag8 af[4][2], bf[2][2];

    // ---- phase 0: quadrant (Mhalf 0, Nhalf 0) ---------------------------
    if (hn) {
      async16(Ag + 0 * a64 + koff, &Ab[nb][0 * 4096 + wave * 512]);
      async16(Ag + 1 * a64 + koff, &Ab[nb][1 * 4096 + wave * 512]);
      asm volatile("s_waitcnt vmcnt(2)" ::: "memory");  // tile t fully landed
    } else {
      asm volatile("s_waitcnt vmcnt(0)" ::: "memory");
    }
    __builtin_amdgcn_s_barrier();
    asm volatile("" ::: "memory");  // fence: no LDS read hoists above publish
#pragma unroll
    for (int i = 0; i < 4; ++i)
#pragma unroll
      for (int kk = 0; kk < 2; ++kk)
        af[i][kk] = *(const frag8*)(&Ab[buf][(wm * 128 + i * 16 + l16) * 64 +
                                             ((kk * 32 + quad * 8) ^ rsw)]);
#pragma unroll
    for (int j = 0; j < 2; ++j)
#pragma unroll
      for (int kk = 0; kk < 2; ++kk)
        bf[j][kk] = *(const frag8*)(&Bb[buf][(wn * 64 + j * 16 + l16) * 64 +
                                             ((kk * 32 + quad * 8) ^ rsw)]);
    __builtin_amdgcn_s_setprio(1);
#pragma unroll
    for (int kk = 0; kk < 2; ++kk)
#pragma unroll
      for (int i = 0; i < 4; ++i)
#pragma unroll
        for (int j = 0; j < 2; ++j)
          acc[i][j] = __builtin_amdgcn_mfma_f32_16x16x32_bf16(af[i][kk], bf[j][kk], acc[i][j], 0, 0, 0);
    __builtin_amdgcn_s_setprio(0);
    __builtin_amdgcn_s_barrier();

    // ---- phase 1: quadrant (Mhalf 0, Nhalf 1) — reuse af ---------------
    if (hn) {
      async16(Ag + 2 * a64 + koff, &Ab[nb][2 * 4096 + wave * 512]);
      async16(Ag + 3 * a64 + koff, &Ab[nb][3 * 4096 + wave * 512]);
    }
#pragma unroll
    for (int j = 0; j < 2; ++j)
#pragma unroll
      for (int kk = 0; kk < 2; ++kk)
        bf[j][kk] = *(const frag8*)(&Bb[buf][(wn * 64 + (j + 2) * 16 + l16) * 64 +
                                             ((kk * 32 + quad * 8) ^ rsw)]);
    __builtin_amdgcn_s_setprio(1);
#pragma unroll
    for (int kk = 0; kk < 2; ++kk)
#pragma unroll
      for (int i = 0; i < 4; ++i)
#pragma unroll
        for (int j = 0; j < 2; ++j)
          acc[i][j + 2] = __builtin_amdgcn_mfma_f32_16x16x32_bf16(af[i][kk], bf[j][kk], acc[i][j + 2], 0, 0, 0);
    __builtin_amdgcn_s_setprio(0);
    __builtin_amdgcn_s_barrier();

    // ---- phase 2: quadrant (Mhalf 1, Nhalf 0) ---------------------------
    if (hn) {
      async16(Bg + 0 * b64 + koff, &Bb[nb][0 * 4096 + wave * 512]);
      async16(Bg + 1 * b64 + koff, &Bb[nb][1 * 4096 + wave * 512]);
    }
#pragma unroll
    for (int i = 0; i < 4; ++i)
#pragma unroll
      for (int kk = 0; kk < 2; ++kk)
        af[i][kk] = *(const frag8*)(&Ab[buf][(wm * 128 + (i + 4) * 16 + l16) * 64 +
                                             ((kk * 32 + quad * 8) ^ rsw)]);
#pragma unroll
    for (int j = 0; j < 2; ++j)
#pragma unroll
      for (int kk = 0; kk < 2; ++kk)
        bf[j][kk] = *(const frag8*)(&Bb[buf][(wn * 64 + j * 16 + l16) * 64 +
                                             ((kk * 32 + quad * 8) ^ rsw)]);
    __builtin_amdgcn_s_setprio(1);
#pragma unroll
    for (int kk = 0; kk < 2; ++kk)
#pragma unroll
      for (int i = 0; i < 4; ++i)
#pragma unroll
        for (int j = 0; j < 2; ++j)
          acc[i + 4][j] = __builtin_amdgcn_mfma_f32_16x16x32_bf16(af[i][kk], bf[j][kk], acc[i + 4][j], 0, 0, 0);
    __builtin_amdgcn_s_setprio(0);
    __builtin_amdgcn_s_barrier();

    // ---- phase 3: quadrant (Mhalf 1, Nhalf 1) — reuse af ---------------
    if (hn) {
      async16(Bg + 2 * b64 + koff, &Bb[nb][2 * 4096 + wave * 512]);
      async16(Bg + 3 * b64 + koff, &Bb[nb][3 * 4096 + wave * 512]);
    }
#pragma unroll
    for (int j = 0; j < 2; ++j)
#pragma unroll
      for (int kk = 0; kk < 2; ++kk)
        bf[j][kk] = *(const frag8*)(&Bb[buf][(wn * 64 + (j + 2) * 16 + l16) * 64 +
                                             ((kk * 32 + quad * 8) ^ rsw)]);
    __builtin_amdgcn_s_setprio(1);
#pragma unroll
    for (int kk = 0; kk < 2; ++kk)
#pragma unroll
      for (int i = 0; i < 4; ++i)
#pragma unroll
        for (int j = 0; j < 2; ++j)
          acc[i + 4][j + 2] = __builtin_amdgcn_mfma_f32_16x16x32_bf16(af[i][kk], bf[j][kk], acc[i + 4][j + 2], 0, 0, 0);
    __builtin_amdgcn_s_setprio(0);
    __builtin_amdgcn_s_barrier();
  }

  // epilogue
  OutT* Ct = C + ((long)bx * 256 + wm * 128) * ldc + (long)by * 256 + wn * 64;
#pragma unroll
  for (int i = 0; i < 8; ++i)
#pragma unroll
    for (int j = 0; j < 4; ++j) {
      int r0 = i * 16 + quad * 4, cc = j * 16 + l16;
#pragma unroll
      for (int r = 0; r < 4; ++r) {
        if constexpr (sizeof(OutT) == 2)
          Ct[(long)(r0 + r) * ldc + cc] = f2bf(acc[i][j][r]);
        else
          Ct[(long)(r0 + r) * ldc + cc] = acc[i][j][r];
      }
    }
}

// ---- m97-style 128x128 GEMM core (kept for N=512 projections) -----------
__device__ __forceinline__ void gemm_core(const u16* __restrict__ A, int lda,
                                          const u16* __restrict__ Bt, int ldb,
                                          int K, u16* As, u16* Bs, f32x4 acc[4][4]) {
  const int tid = threadIdx.x;
  const int lane = tid & 63, wave = tid >> 6;
  const int wr = wave >> 1, wc = wave & 1;
  const int quad = lane >> 4, l16 = lane & 15;
#pragma unroll
  for (int i = 0; i < 4; ++i)
#pragma unroll
    for (int j = 0; j < 4; ++j) acc[i][j] = (f32x4){0.f, 0.f, 0.f, 0.f};

  const int row0 = tid >> 2, offc = (tid & 3) * 8;  // 128 rows x 32 k, 16B chunks
  for (int k0 = 0; k0 < K; k0 += 32) {
#pragma unroll
    for (int r = 0; r < 2; ++r) {
      int row = r * 64 + row0;
      async16(A + (long)row * lda + k0 + offc, As + r * 2048 + wave * 512);
      async16(Bt + (long)row * ldb + k0 + offc, Bs + r * 2048 + wave * 512);
    }
    __syncthreads();
    frag8 af[4], bf[4];
#pragma unroll
    for (int i = 0; i < 4; ++i)
      af[i] = *(const frag8*)(As + (wr * 64 + i * 16 + l16) * 32 + quad * 8);
#pragma unroll
    for (int j = 0; j < 4; ++j)
      bf[j] = *(const frag8*)(Bs + (wc * 64 + j * 16 + l16) * 32 + quad * 8);
#pragma unroll
    for (int i = 0; i < 4; ++i)
#pragma unroll
      for (int j = 0; j < 4; ++j)
        acc[i][j] = __builtin_amdgcn_mfma_f32_16x16x32_bf16(af[i], bf[j], acc[i][j], 0, 0, 0);
    __syncthreads();
  }
}

#define EPI_COORDS                                             \
  const int lane = threadIdx.x & 63, wave = threadIdx.x >> 6;  \
  const int wr = wave >> 1, wc = wave & 1;                     \
  const int quad = lane >> 4, l16 = lane & 15;

__global__ __launch_bounds__(256) void k_gemm_bf16(const u16* __restrict__ A, int lda,
                                                   const u16* __restrict__ Bt, int ldb,
                                                   u16* __restrict__ C, int ldc, int K) {
  __shared__ alignas(16) u16 smem[2 * TILE * 32];
  int bx, by; xcd_map(bx, by);
  f32x4 acc[4][4];
  gemm_core(A + (long)bx * TILE * lda, lda,
            Bt + (long)by * TILE * ldb, ldb, K, smem, smem + TILE * 32, acc);
  EPI_COORDS
  u16* Ct = C + (long)bx * TILE * ldc + (long)by * TILE;
#pragma unroll
  for (int i = 0; i < 4; ++i)
#pragma unroll
    for (int j = 0; j < 4; ++j) {
      int r0 = wr * 64 + i * 16 + quad * 4, cc = wc * 64 + j * 16 + l16;
#pragma unroll
      for (int r = 0; r < 4; ++r) Ct[(long)(r0 + r) * ldc + cc] = f2bf(acc[i][j][r]);
    }
}

// writes C^T: contiguous 4-element store per acc tile (for V^T layout)
__global__ __launch_bounds__(256) void k_gemm_bf16t(const u16* __restrict__ A, int lda,
                                                    const u16* __restrict__ Bt, int ldb,
                                                    u16* __restrict__ Ct, int ldct, int K) {
  __shared__ alignas(16) u16 smem[2 * TILE * 32];
  int bx, by; xcd_map(bx, by);
  f32x4 acc[4][4];
  gemm_core(A + (long)bx * TILE * lda, lda,
            Bt + (long)by * TILE * ldb, ldb, K, smem, smem + TILE * 32, acc);
  EPI_COORDS
  u16* Cb = Ct + (long)by * TILE * ldct + (long)bx * TILE;
#pragma unroll
  for (int i = 0; i < 4; ++i)
#pragma unroll
    for (int j = 0; j < 4; ++j) {
      int n = wc * 64 + j * 16 + l16, m0 = wr * 64 + i * 16 + quad * 4;
      ushort4 o;
      o.x = f2bf(acc[i][j][0]); o.y = f2bf(acc[i][j][1]);
      o.z = f2bf(acc[i][j][2]); o.w = f2bf(acc[i][j][3]);
      *(ushort4*)(Cb + (long)n * ldct + m0) = o;
    }
}

// ---- fused local-window attention (unchanged from R4) -------------------
__global__ __launch_bounds__(256, 2) void k_attn(const u16* __restrict__ qb,
                                                 const u16* __restrict__ kb,
                                                 const u16* __restrict__ vT,
                                                 u16* __restrict__ O) {
  __shared__ alignas(16) u16 Ks[2][64 * 128];  // [key][hd]; P overlays cur after S
  __shared__ alignas(16) u16 Vs[2][128 * 64];  // [hd][key]
  const int tid = threadIdx.x, lane = tid & 63, wave = tid >> 6;
  const int quad = lane >> 4, l16 = lane & 15;

  // XCD-group decode
  const int id = blockIdx.x + 4 * blockIdx.y + 32 * blockIdx.z;  // 0..1023
  const int g = (id & 7) | ((id >> 7) << 3);                     // group 0..63
  const int w = (id >> 3) & 15;                                  // member 0..15
  const int hk = g & 3, blk = (g >> 2) & 7, b = g >> 5;
  const int h = hk * 4 + (w & 3), qi = w >> 2;

  const long tok_q = (long)b * 4096 + blk * 512 + qi * 128;
  const float scale = 0.08838834764831845f;  // 1/sqrt(128)

  frag8 qf[2][4];
#pragma unroll
  for (int i = 0; i < 2; ++i)
#pragma unroll
    for (int kt = 0; kt < 4; ++kt)
      qf[i][kt] = *(const frag8*)(qb + (tok_q + wave * 32 + i * 16 + l16) * 2048 +
                                  h * 128 + kt * 32 + quad * 8);

  f32x4 o_acc[2][8];
  float m_r[2][4], l_r[2][4];
#pragma unroll
  for (int i = 0; i < 2; ++i) {
#pragma unroll
    for (int j = 0; j < 8; ++j) o_acc[i][j] = (f32x4){0.f, 0.f, 0.f, 0.f};
#pragma unroll
    for (int r = 0; r < 4; ++r) { m_r[i][r] = -1e30f; l_r[i][r] = 0.f; }
  }

  const int rsw = (l16 & 7) << 3;  // read-side XOR (u16)

  auto stage = [&](int buf, int ci) {
    const long tk = (long)b * 4096 + (blk - 1) * 512 + ci * 64;
#pragma unroll
    for (int c = 0; c < 4; ++c) {
      const int idx = (wave * 4 + c) * 512 + lane * 8;  // u16 index, linear
      {  // K: row = idx/128, col = idx%128
        int row = idx >> 7, col = idx & 127;
        async16(kb + (tk + row) * 512 + hk * 128 + (col ^ ((row & 7) << 3)),
                &Ks[buf][(wave * 4 + c) * 512]);
      }
      {  // V: row = idx/64, col = idx%64
        int row = idx >> 6, col = idx & 63;
        async16(vT + ((long)hk * 128 + row) * 8192 + tk + (col ^ ((row & 7) << 3)),
                &Vs[buf][(wave * 4 + c) * 512]);
      }
    }
  };

  const int c0 = blk ? 2 * qi : 8, c1 = 9 + 2 * qi;
  int cur = 0;
  stage(0, c0);
  __syncthreads();  // drain prologue staging

  for (int ci = c0; ci <= c1; ++ci) {
    if (ci < c1) stage(cur ^ 1, ci + 1);  // issue-early prefetch

    f32x4 s_acc[2][4];
#pragma unroll
    for (int i = 0; i < 2; ++i)
#pragma unroll
      for (int j = 0; j < 4; ++j) s_acc[i][j] = (f32x4){0.f, 0.f, 0.f, 0.f};
#pragma unroll
    for (int kt = 0; kt < 4; ++kt) {
      frag8 bfr[4];
#pragma unroll
      for (int j = 0; j < 4; ++j)
        bfr[j] = *(const frag8*)(&Ks[cur][(j * 16 + l16) * 128 + ((kt * 32 + quad * 8) ^ rsw)]);
#pragma unroll
      for (int i = 0; i < 2; ++i)
#pragma unroll
        for (int j = 0; j < 4; ++j)
          s_acc[i][j] = __builtin_amdgcn_mfma_f32_16x16x32_bf16(qf[i][kt], bfr[j], s_acc[i][j], 0, 0, 0);
    }

    const bool prev = (ci < 8);
    const int doff = (prev ? ci * 64 : (ci - 8) * 64) - qi * 128;
    float mc[2][4];
#pragma unroll
    for (int i = 0; i < 2; ++i)
#pragma unroll
      for (int r = 0; r < 4; ++r) mc[i][r] = -1e30f;
#pragma unroll
    for (int i = 0; i < 2; ++i)
#pragma unroll
      for (int j = 0; j < 4; ++j)
#pragma unroll
        for (int r = 0; r < 4; ++r) {
          int rl = wave * 32 + i * 16 + quad * 4 + r;
          int lk = j * 16 + l16;
          bool ok = prev ? (lk + doff > rl) : (lk + doff <= rl);
          float s = ok ? s_acc[i][j][r] * scale : -1e30f;
          s_acc[i][j][r] = s;
          mc[i][r] = fmaxf(mc[i][r], s);
        }
#pragma unroll
    for (int o = 1; o < 16; o <<= 1)
#pragma unroll
      for (int i = 0; i < 2; ++i)
#pragma unroll
        for (int r = 0; r < 4; ++r)
          mc[i][r] = fmaxf(mc[i][r], __shfl_xor(mc[i][r], o));

    float alpha[2][4];
#pragma unroll
    for (int i = 0; i < 2; ++i)
#pragma unroll
      for (int r = 0; r < 4; ++r) {
        float mn = fmaxf(m_r[i][r], mc[i][r]);
        alpha[i][r] = __expf(m_r[i][r] - mn);
        m_r[i][r] = mn;
        l_r[i][r] *= alpha[i][r];
      }
#pragma unroll
    for (int i = 0; i < 2; ++i)
#pragma unroll
      for (int j = 0; j < 8; ++j)
#pragma unroll
        for (int r = 0; r < 4; ++r) o_acc[i][j][r] *= alpha[i][r];

    float ps[2][4];
#pragma unroll
    for (int i = 0; i < 2; ++i)
#pragma unroll
      for (int r = 0; r < 4; ++r) ps[i][r] = 0.f;
#pragma unroll
    for (int i = 0; i < 2; ++i)
#pragma unroll
      for (int j = 0; j < 4; ++j)
#pragma unroll
        for (int r = 0; r < 4; ++r) {
          float s = s_acc[i][j][r];
          float e = __expf(s - m_r[i][r]);
          e = (s == -1e30f) ? 0.f : e;
          s_acc[i][j][r] = e;
          ps[i][r] += e;
        }
#pragma unroll
    for (int o = 1; o < 16; o <<= 1)
#pragma unroll
      for (int i = 0; i < 2; ++i)
#pragma unroll
        for (int r = 0; r < 4; ++r) ps[i][r] += __shfl_xor(ps[i][r], o);
#pragma unroll
    for (int i = 0; i < 2; ++i)
#pragma unroll
      for (int r = 0; r < 4; ++r) l_r[i][r] += ps[i][r];

    __syncthreads();  // Ks[cur] reads done -> P may overlay; prefetch drained

    u16* PsW = &Ks[cur][wave * 2048];
#pragma unroll
    for (int i = 0; i < 2; ++i)
#pragma unroll
      for (int r = 0; r < 4; ++r) {
        int xw = ((quad * 4 + r) & 7) << 3;
#pragma unroll
        for (int j = 0; j < 4; ++j)
          PsW[(i * 16 + quad * 4 + r) * 64 + ((j * 16 + l16) ^ xw)] = f2bf(s_acc[i][j][r]);
      }

#pragma unroll
    for (int kt = 0; kt < 2; ++kt) {
      frag8 pf[2], vf[8];
#pragma unroll
      for (int i = 0; i < 2; ++i)
        pf[i] = *(const frag8*)(PsW + (i * 16 + l16) * 64 + ((kt * 32 + quad * 8) ^ rsw));
#pragma unroll
      for (int j = 0; j < 8; ++j)
        vf[j] = *(const frag8*)(&Vs[cur][(j * 16 + l16) * 64 + ((kt * 32 + quad * 8) ^ rsw)]);
#pragma unroll
      for (int i = 0; i < 2; ++i)
#pragma unroll
        for (int j = 0; j < 8; ++j)
          o_acc[i][j] = __builtin_amdgcn_mfma_f32_16x16x32_bf16(pf[i], vf[j], o_acc[i][j], 0, 0, 0);
    }
    __syncthreads();
    cur ^= 1;
  }

  float inv[2][4];
#pragma unroll
  for (int i = 0; i < 2; ++i)
#pragma unroll
    for (int r = 0; r < 4; ++r) inv[i][r] = 1.0f / l_r[i][r];
  u16* Ob = &Ks[0][0];  // 32KB contiguous: [128 row][128 u16]
#pragma unroll
  for (int i = 0; i < 2; ++i)
#pragma unroll
    for (int j = 0; j < 8; ++j)
#pragma unroll
      for (int r = 0; r < 4; ++r)
        Ob[(wave * 32 + i * 16 + quad * 4 + r) * 128 + j * 16 + l16] =
            f2bf(o_acc[i][j][r] * inv[i][r]);
  __syncthreads();
#pragma unroll
  for (int p = 0; p < 8; ++p) {
    int idx = p * 256 + tid;
    int row = idx >> 4, col = (idx & 15) * 8;
    *(frag8*)(O + (tok_q + row) * 2048 + h * 128 + col) = *(const frag8*)(Ob + row * 128 + col);
  }
}

__global__ void k_convert(const float4* __restrict__ x, ushort4* __restrict__ xb) {
  int i = blockIdx.x * 256 + threadIdx.x;
  float4 f = x[i];
  ushort4 o;
  o.x = f2bf(f.x); o.y = f2bf(f.y); o.z = f2bf(f.z); o.w = f2bf(f.w);
  xb[i] = o;
}

// W [K,N] fp32 -> W^T [N,K] bf16
__global__ void k_transpose(const float* __restrict__ W, u16* __restrict__ WT, int K, int N) {
  __shared__ float sh[32][33];
  int n0 = blockIdx.x * 32, k0 = blockIdx.y * 32;
  int tx = threadIdx.x, ty = threadIdx.y;  // (32, 8)
#pragma unroll
  for (int i = 0; i < 32; i += 8) sh[ty + i][tx] = W[(long)(k0 + ty + i) * N + n0 + tx];
  __syncthreads();
#pragma unroll
  for (int i = 0; i < 32; i += 8) WT[(long)(n0 + ty + i) * K + k0 + tx] = f2bf(sh[tx][ty + i]);
}

extern "C" void kernel_launch(void* const* d_in, const int* in_sizes, int n_in,
                              void* d_out, int out_size, void* d_ws, size_t ws_size,
                              hipStream_t stream) {
  const float* x  = (const float*)d_in[0];
  const float* Wq = (const float*)d_in[1];
  const float* Wk = (const float*)d_in[2];
  const float* Wv = (const float*)d_in[3];
  const float* Wo = (const float*)d_in[4];
  float* out = (float*)d_out;

  const long BT = 8192, D = 2048, NKV = 512;
  size_t off = 0;
  auto alloc = [&](size_t bytes) -> char* {
    off = (off + 255) & ~(size_t)255;
    char* p = (char*)d_ws + off;
    off += bytes;
    return p;
  };

  u16* xb  = (u16*)alloc((size_t)BT * D * 2);  // reused as attention output
  u16* WqT = (u16*)alloc((size_t)D * D * 2);
  u16* WkT = (u16*)alloc((size_t)NKV * D * 2);
  u16* WvT = (u16*)alloc((size_t)NKV * D * 2);
  u16* WoT = (u16*)alloc((size_t)D * D * 2);
  u16* qb  = (u16*)alloc((size_t)BT * D * 2);
  u16* kb  = (u16*)alloc((size_t)BT * NKV * 2);
  u16* vT  = (u16*)alloc((size_t)NKV * BT * 2);
  u16* Oa  = xb;

  k_convert<<<16384, 256, 0, stream>>>((const float4*)x, (ushort4*)xb);
  dim3 tb(32, 8);
  k_transpose<<<dim3(64, 64), tb, 0, stream>>>(Wq, WqT, 2048, 2048);
  k_transpose<<<dim3(16, 64), tb, 0, stream>>>(Wk, WkT, 2048, 512);
  k_transpose<<<dim3(16, 64), tb, 0, stream>>>(Wv, WvT, 2048, 512);
  k_transpose<<<dim3(64, 64), tb, 0, stream>>>(Wo, WoT, 2048, 2048);

  k_gemm256<u16><<<dim3(32, 8), 512, 0, stream>>>(xb, 2048, WqT, 2048, qb, 2048, 2048);
  k_gemm_bf16 <<<dim3(64, 4),  256, 0, stream>>>(xb, 2048, WkT, 2048, kb, 512, 2048);
  k_gemm_bf16t<<<dim3(64, 4),  256, 0, stream>>>(xb, 2048, WvT, 2048, vT, 8192, 2048);

  k_attn<<<dim3(4, 8, 32), 256, 0, stream>>>(qb, kb, vT, Oa);

  k_gemm256<float><<<dim3(32, 8), 512, 0, stream>>>(Oa, 2048, WoT, 2048, out, 2048, 2048);
}

// Round 4
// 459.151 us; speedup vs baseline: 1.2747x; 1.1312x over previous
//
#include <hip/hip_runtime.h>
#include <stdint.h>

// LocalWindowAttention: B=2,T=4096,D=2048,H=16,HK=4,HD=128,WIN=512
// R6: (1) k_gemm256: issue all 8 next-tile loads at phase 0 + vmcnt(8)
//     (full K-tile of latency slack vs ~1 phase before); oscale epilogue.
//     (2) Q pre-scaled at projection -> attn drops per-chunk scale muls.
//     (3) gemm_core (K/V proj): double-buffered + counted vmcnt(4) + raw
//     barriers (T3 minimum 2-phase).
//     (4) attn: defer-max (T13, THR=8, exact); mid barrier without vmcnt
//     drain so PV overlaps the next chunk's prefetch; drain moved to end.

typedef unsigned short u16;
typedef __attribute__((ext_vector_type(8))) short frag8;   // 8 bf16 = 4 VGPRs
typedef __attribute__((ext_vector_type(4))) float f32x4;   // MFMA acc

#define TILE 128

__device__ __forceinline__ u16 f2bf(float f) {
  union { float f; unsigned u; } c; c.f = f;
  unsigned u = c.u;
  return (u16)((u + 0x7fffu + ((u >> 16) & 1u)) >> 16);
}

// async global->LDS, 16B per lane; LDS dest = wave-uniform base + lane*16
__device__ __forceinline__ void async16(const u16* g, u16* l) {
  __builtin_amdgcn_global_load_lds((const __attribute__((address_space(1))) void*)g,
                                   (__attribute__((address_space(3))) void*)l, 16, 0, 0);
}

// T1: XCD-chunked remap. Requires gridDim.x % 8 == 0.
__device__ __forceinline__ void xcd_map(int& bx, int& by) {
  const int gx = gridDim.x;
  const int cx = gx >> 3;
  int id = blockIdx.y * gx + blockIdx.x;
  int xcd = id & 7, local = id >> 3;
  bx = xcd * cx + (local % cx);
  by = local / cx;
}

// ======================= 256^2 4-phase GEMM ==============================
// A [M,K] row-major bf16, Bt = B^T [N,K] row-major bf16, C [M,N] (u16|f32).
// Tile 256x256, BK=64, double-buffered. LDS [256 rows][64 k] bf16 with
// col ^= (row&7)<<3 swizzle via inverse-swizzled global src (linear dest).
// All 8 next-tile loads issued at phase 0; wait vmcnt(8) -> every load has
// a full K-tile (~4 phases) in flight before its drain point.
template <typename OutT>
__global__ __launch_bounds__(512, 2) void k_gemm256(const u16* __restrict__ A, int lda,
                                                    const u16* __restrict__ Bt, int ldb,
                                                    OutT* __restrict__ C, int ldc, int K,
                                                    float oscale) {
  __shared__ alignas(16) u16 Ab[2][256 * 64];  // 64 KB
  __shared__ alignas(16) u16 Bb[2][256 * 64];  // 64 KB
  const int tid = threadIdx.x, lane = tid & 63, wave = tid >> 6;
  const int wm = wave >> 2, wn = wave & 3;     // 2M x 4N wave grid
  const int quad = lane >> 4, l16 = lane & 15;

  int bx, by;
  xcd_map(bx, by);

  // staging coords: issue c, wave w, lane l -> row = c*64+w*8+(l>>3),
  // src col = ((l&7)^(l>>3))*8  (row&7 == l>>3 -> involution holds)
  const int rsub = wave * 8 + (lane >> 3);
  const int csub = ((lane & 7) ^ (lane >> 3)) * 8;
  const u16* Ag = A + ((long)bx * 256 + rsub) * lda + csub;
  const u16* Bg = Bt + ((long)by * 256 + rsub) * ldb + csub;
  const long a64 = (long)64 * lda, b64 = (long)64 * ldb;

  const int rsw = (l16 & 7) << 3;  // read-side XOR (u16 units)

  f32x4 acc[8][4];
#pragma unroll
  for (int i = 0; i < 8; ++i)
#pragma unroll
    for (int j = 0; j < 4; ++j) acc[i][j] = (f32x4){0.f, 0.f, 0.f, 0.f};

  const int nt = K >> 6;

  // prologue: stage tile 0 (8 inst/wave)
#pragma unroll
  for (int c = 0; c < 4; ++c) {
    async16(Ag + c * a64, &Ab[0][c * 4096 + wave * 512]);
    async16(Bg + c * b64, &Bb[0][c * 4096 + wave * 512]);
  }

  for (int t = 0; t < nt; ++t) {
    const int buf = t & 1, nb = buf ^ 1;
    const long koff = (long)(t + 1) << 6;
    frag8 af[4][2], bf[2][2];

    // ---- phase 0: issue ALL next-tile loads, then drain tile t ----------
    if (t + 1 < nt) {
#pragma unroll
      for (int c = 0; c < 4; ++c) {
        async16(Ag + c * a64 + koff, &Ab[nb][c * 4096 + wave * 512]);
        async16(Bg + c * b64 + koff, &Bb[nb][c * 4096 + wave * 512]);
      }
      asm volatile("s_waitcnt vmcnt(8)" ::: "memory");  // tile t fully landed
    } else {
      asm volatile("s_waitcnt vmcnt(0)" ::: "memory");
    }
    __builtin_amdgcn_s_barrier();
    asm volatile("" ::: "memory");

    // quadrant (M0, N0)
#pragma unroll
    for (int i = 0; i < 4; ++i)
#pragma unroll
      for (int kk = 0; kk < 2; ++kk)
        af[i][kk] = *(const frag8*)(&Ab[buf][(wm * 128 + i * 16 + l16) * 64 +
                                             ((kk * 32 + quad * 8) ^ rsw)]);
#pragma unroll
    for (int j = 0; j < 2; ++j)
#pragma unroll
      for (int kk = 0; kk < 2; ++kk)
        bf[j][kk] = *(const frag8*)(&Bb[buf][(wn * 64 + j * 16 + l16) * 64 +
                                             ((kk * 32 + quad * 8) ^ rsw)]);
    __builtin_amdgcn_s_setprio(1);
#pragma unroll
    for (int kk = 0; kk < 2; ++kk)
#pragma unroll
      for (int i = 0; i < 4; ++i)
#pragma unroll
        for (int j = 0; j < 2; ++j)
          acc[i][j] = __builtin_amdgcn_mfma_f32_16x16x32_bf16(af[i][kk], bf[j][kk], acc[i][j], 0, 0, 0);
    __builtin_amdgcn_s_setprio(0);
    __builtin_amdgcn_s_barrier();

    // quadrant (M0, N1) — reuse af
#pragma unroll
    for (int j = 0; j < 2; ++j)
#pragma unroll
      for (int kk = 0; kk < 2; ++kk)
        bf[j][kk] = *(const frag8*)(&Bb[buf][(wn * 64 + (j + 2) * 16 + l16) * 64 +
                                             ((kk * 32 + quad * 8) ^ rsw)]);
    __builtin_amdgcn_s_setprio(1);
#pragma unroll
    for (int kk = 0; kk < 2; ++kk)
#pragma unroll
      for (int i = 0; i < 4; ++i)
#pragma unroll
        for (int j = 0; j < 2; ++j)
          acc[i][j + 2] = __builtin_amdgcn_mfma_f32_16x16x32_bf16(af[i][kk], bf[j][kk], acc[i][j + 2], 0, 0, 0);
    __builtin_amdgcn_s_setprio(0);
    __builtin_amdgcn_s_barrier();

    // quadrant (M1, N0)
#pragma unroll
    for (int i = 0; i < 4; ++i)
#pragma unroll
      for (int kk = 0; kk < 2; ++kk)
        af[i][kk] = *(const frag8*)(&Ab[buf][(wm * 128 + (i + 4) * 16 + l16) * 64 +
                                             ((kk * 32 + quad * 8) ^ rsw)]);
#pragma unroll
    for (int j = 0; j < 2; ++j)
#pragma unroll
      for (int kk = 0; kk < 2; ++kk)
        bf[j][kk] = *(const frag8*)(&Bb[buf][(wn * 64 + j * 16 + l16) * 64 +
                                             ((kk * 32 + quad * 8) ^ rsw)]);
    __builtin_amdgcn_s_setprio(1);
#pragma unroll
    for (int kk = 0; kk < 2; ++kk)
#pragma unroll
      for (int i = 0; i < 4; ++i)
#pragma unroll
        for (int j = 0; j < 2; ++j)
          acc[i + 4][j] = __builtin_amdgcn_mfma_f32_16x16x32_bf16(af[i][kk], bf[j][kk], acc[i + 4][j], 0, 0, 0);
    __builtin_amdgcn_s_setprio(0);
    __builtin_amdgcn_s_barrier();

    // quadrant (M1, N1) — reuse af
#pragma unroll
    for (int j = 0; j < 2; ++j)
#pragma unroll
      for (int kk = 0; kk < 2; ++kk)
        bf[j][kk] = *(const frag8*)(&Bb[buf][(wn * 64 + (j + 2) * 16 + l16) * 64 +
                                             ((kk * 32 + quad * 8) ^ rsw)]);
    __builtin_amdgcn_s_setprio(1);
#pragma unroll
    for (int kk = 0; kk < 2; ++kk)
#pragma unroll
      for (int i = 0; i < 4; ++i)
#pragma unroll
        for (int j = 0; j < 2; ++j)
          acc[i + 4][j + 2] = __builtin_amdgcn_mfma_f32_16x16x32_bf16(af[i][kk], bf[j][kk], acc[i + 4][j + 2], 0, 0, 0);
    __builtin_amdgcn_s_setprio(0);
    __builtin_amdgcn_s_barrier();
  }

  // epilogue (oscale folded; used to pre-scale Q by 1/sqrt(HD))
  OutT* Ct = C + ((long)bx * 256 + wm * 128) * ldc + (long)by * 256 + wn * 64;
#pragma unroll
  for (int i = 0; i < 8; ++i)
#pragma unroll
    for (int j = 0; j < 4; ++j) {
      int r0 = i * 16 + quad * 4, cc = j * 16 + l16;
#pragma unroll
      for (int r = 0; r < 4; ++r) {
        float v = acc[i][j][r] * oscale;
        if constexpr (sizeof(OutT) == 2)
          Ct[(long)(r0 + r) * ldc + cc] = f2bf(v);
        else
          Ct[(long)(r0 + r) * ldc + cc] = v;
      }
    }
}

// ---- 128x128 GEMM core, now double-buffered + counted vmcnt (T3-min) ----
// As/Bs each point at 2 x 128x32 u16 buffers (buf offset = buf*4096).
__device__ __forceinline__ void gemm_core(const u16* __restrict__ A, int lda,
                                          const u16* __restrict__ Bt, int ldb,
                                          int K, u16* As, u16* Bs, f32x4 acc[4][4]) {
  const int tid = threadIdx.x;
  const int lane = tid & 63, wave = tid >> 6;
  const int wr = wave >> 1, wc = wave & 1;
  const int quad = lane >> 4, l16 = lane & 15;
#pragma unroll
  for (int i = 0; i < 4; ++i)
#pragma unroll
    for (int j = 0; j < 4; ++j) acc[i][j] = (f32x4){0.f, 0.f, 0.f, 0.f};

  const int row0 = tid >> 2, offc = (tid & 3) * 8;  // 128 rows x 32 k, 16B chunks
  const int nt = K >> 5;

  // prologue: tile 0
#pragma unroll
  for (int r = 0; r < 2; ++r) {
    int row = r * 64 + row0;
    async16(A + (long)row * lda + offc, As + r * 2048 + wave * 512);
    async16(Bt + (long)row * ldb + offc, Bs + r * 2048 + wave * 512);
  }

  for (int t = 0; t < nt; ++t) {
    const int bo = (t & 1) * 4096, nbo = bo ^ 4096;
    if (t + 1 < nt) {
      const int k0 = (t + 1) * 32;
#pragma unroll
      for (int r = 0; r < 2; ++r) {
        int row = r * 64 + row0;
        async16(A + (long)row * lda + k0 + offc, As + nbo + r * 2048 + wave * 512);
        async16(Bt + (long)row * ldb + k0 + offc, Bs + nbo + r * 2048 + wave * 512);
      }
      asm volatile("s_waitcnt vmcnt(4)" ::: "memory");  // tile t landed
    } else {
      asm volatile("s_waitcnt vmcnt(0)" ::: "memory");
    }
    __builtin_amdgcn_s_barrier();
    asm volatile("" ::: "memory");

    frag8 af[4], bf[4];
#pragma unroll
    for (int i = 0; i < 4; ++i)
      af[i] = *(const frag8*)(As + bo + (wr * 64 + i * 16 + l16) * 32 + quad * 8);
#pragma unroll
    for (int j = 0; j < 4; ++j)
      bf[j] = *(const frag8*)(Bs + bo + (wc * 64 + j * 16 + l16) * 32 + quad * 8);
#pragma unroll
    for (int i = 0; i < 4; ++i)
#pragma unroll
      for (int j = 0; j < 4; ++j)
        acc[i][j] = __builtin_amdgcn_mfma_f32_16x16x32_bf16(af[i], bf[j], acc[i][j], 0, 0, 0);
    asm volatile("" ::: "memory");
    __builtin_amdgcn_s_barrier();  // all reads of buf done before restage
  }
}

#define EPI_COORDS                                             \
  const int lane = threadIdx.x & 63, wave = threadIdx.x >> 6;  \
  const int wr = wave >> 1, wc = wave & 1;                     \
  const int quad = lane >> 4, l16 = lane & 15;

__global__ __launch_bounds__(256) void k_gemm_bf16(const u16* __restrict__ A, int lda,
                                                   const u16* __restrict__ Bt, int ldb,
                                                   u16* __restrict__ C, int ldc, int K) {
  __shared__ alignas(16) u16 smem[4 * TILE * 32];  // 2 bufs x (A,B)
  int bx, by; xcd_map(bx, by);
  f32x4 acc[4][4];
  gemm_core(A + (long)bx * TILE * lda, lda,
            Bt + (long)by * TILE * ldb, ldb, K, smem, smem + 2 * TILE * 32, acc);
  EPI_COORDS
  u16* Ct = C + (long)bx * TILE * ldc + (long)by * TILE;
#pragma unroll
  for (int i = 0; i < 4; ++i)
#pragma unroll
    for (int j = 0; j < 4; ++j) {
      int r0 = wr * 64 + i * 16 + quad * 4, cc = wc * 64 + j * 16 + l16;
#pragma unroll
      for (int r = 0; r < 4; ++r) Ct[(long)(r0 + r) * ldc + cc] = f2bf(acc[i][j][r]);
    }
}

// writes C^T: contiguous 4-element store per acc tile (for V^T layout)
__global__ __launch_bounds__(256) void k_gemm_bf16t(const u16* __restrict__ A, int lda,
                                                    const u16* __restrict__ Bt, int ldb,
                                                    u16* __restrict__ Ct, int ldct, int K) {
  __shared__ alignas(16) u16 smem[4 * TILE * 32];
  int bx, by; xcd_map(bx, by);
  f32x4 acc[4][4];
  gemm_core(A + (long)bx * TILE * lda, lda,
            Bt + (long)by * TILE * ldb, ldb, K, smem, smem + 2 * TILE * 32, acc);
  EPI_COORDS
  u16* Cb = Ct + (long)by * TILE * ldct + (long)bx * TILE;
#pragma unroll
  for (int i = 0; i < 4; ++i)
#pragma unroll
    for (int j = 0; j < 4; ++j) {
      int n = wc * 64 + j * 16 + l16, m0 = wr * 64 + i * 16 + quad * 4;
      ushort4 o;
      o.x = f2bf(acc[i][j][0]); o.y = f2bf(acc[i][j][1]);
      o.z = f2bf(acc[i][j][2]); o.w = f2bf(acc[i][j][3]);
      *(ushort4*)(Cb + (long)n * ldct + m0) = o;
    }
}

// ---- fused local-window attention --------------------------------------
// (see R4 header for decode/layout). This round: Q arrives PRE-SCALED; mid
// barrier is a raw s_barrier (no vmcnt drain -> PV overlaps prefetch);
// vmcnt(0) drain moved to the end barrier; defer-max (T13, THR=8).
__global__ __launch_bounds__(256, 2) void k_attn(const u16* __restrict__ qb,
                                                 const u16* __restrict__ kb,
                                                 const u16* __restrict__ vT,
                                                 u16* __restrict__ O) {
  __shared__ alignas(16) u16 Ks[2][64 * 128];  // [key][hd]; P overlays cur after S
  __shared__ alignas(16) u16 Vs[2][128 * 64];  // [hd][key]
  const int tid = threadIdx.x, lane = tid & 63, wave = tid >> 6;
  const int quad = lane >> 4, l16 = lane & 15;

  // XCD-group decode
  const int id = blockIdx.x + 4 * blockIdx.y + 32 * blockIdx.z;  // 0..1023
  const int g = (id & 7) | ((id >> 7) << 3);                     // group 0..63
  const int w = (id >> 3) & 15;                                  // member 0..15
  const int hk = g & 3, blk = (g >> 2) & 7, b = g >> 5;
  const int h = hk * 4 + (w & 3), qi = w >> 2;

  const long tok_q = (long)b * 4096 + blk * 512 + qi * 128;

  frag8 qf[2][4];
#pragma unroll
  for (int i = 0; i < 2; ++i)
#pragma unroll
    for (int kt = 0; kt < 4; ++kt)
      qf[i][kt] = *(const frag8*)(qb + (tok_q + wave * 32 + i * 16 + l16) * 2048 +
                                  h * 128 + kt * 32 + quad * 8);

  f32x4 o_acc[2][8];
  float m_r[2][4], l_r[2][4];
#pragma unroll
  for (int i = 0; i < 2; ++i) {
#pragma unroll
    for (int j = 0; j < 8; ++j) o_acc[i][j] = (f32x4){0.f, 0.f, 0.f, 0.f};
#pragma unroll
    for (int r = 0; r < 4; ++r) { m_r[i][r] = -1e30f; l_r[i][r] = 0.f; }
  }

  const int rsw = (l16 & 7) << 3;  // read-side XOR (u16)

  auto stage = [&](int buf, int ci) {
    const long tk = (long)b * 4096 + (blk - 1) * 512 + ci * 64;
#pragma unroll
    for (int c = 0; c < 4; ++c) {
      const int idx = (wave * 4 + c) * 512 + lane * 8;  // u16 index, linear
      {  // K: row = idx/128, col = idx%128
        int row = idx >> 7, col = idx & 127;
        async16(kb + (tk + row) * 512 + hk * 128 + (col ^ ((row & 7) << 3)),
                &Ks[buf][(wave * 4 + c) * 512]);
      }
      {  // V: row = idx/64, col = idx%64
        int row = idx >> 6, col = idx & 63;
        async16(vT + ((long)hk * 128 + row) * 8192 + tk + (col ^ ((row & 7) << 3)),
                &Vs[buf][(wave * 4 + c) * 512]);
      }
    }
  };

  const int c0 = blk ? 2 * qi : 8, c1 = 9 + 2 * qi;
  int cur = 0;
  stage(0, c0);
  asm volatile("s_waitcnt vmcnt(0)" ::: "memory");
  __builtin_amdgcn_s_barrier();
  asm volatile("" ::: "memory");

  for (int ci = c0; ci <= c1; ++ci) {
    if (ci < c1) stage(cur ^ 1, ci + 1);  // issue-early prefetch

    f32x4 s_acc[2][4];
#pragma unroll
    for (int i = 0; i < 2; ++i)
#pragma unroll
      for (int j = 0; j < 4; ++j) s_acc[i][j] = (f32x4){0.f, 0.f, 0.f, 0.f};
#pragma unroll
    for (int kt = 0; kt < 4; ++kt) {
      frag8 bfr[4];
#pragma unroll
      for (int j = 0; j < 4; ++j)
        bfr[j] = *(const frag8*)(&Ks[cur][(j * 16 + l16) * 128 + ((kt * 32 + quad * 8) ^ rsw)]);
#pragma unroll
      for (int i = 0; i < 2; ++i)
#pragma unroll
        for (int j = 0; j < 4; ++j)
          s_acc[i][j] = __builtin_amdgcn_mfma_f32_16x16x32_bf16(qf[i][kt], bfr[j], s_acc[i][j], 0, 0, 0);
    }

    // mask (Q pre-scaled -> no scale mul) + per-row chunk max
    const bool prev = (ci < 8);
    const int doff = (prev ? ci * 64 : (ci - 8) * 64) - qi * 128;
    float mc[2][4];
#pragma unroll
    for (int i = 0; i < 2; ++i)
#pragma unroll
      for (int r = 0; r < 4; ++r) mc[i][r] = -1e30f;
#pragma unroll
    for (int i = 0; i < 2; ++i)
#pragma unroll
      for (int j = 0; j < 4; ++j)
#pragma unroll
        for (int r = 0; r < 4; ++r) {
          int rl = wave * 32 + i * 16 + quad * 4 + r;
          int lk = j * 16 + l16;
          bool ok = prev ? (lk + doff > rl) : (lk + doff <= rl);
          float s = ok ? s_acc[i][j][r] : -1e30f;
          s_acc[i][j][r] = s;
          mc[i][r] = fmaxf(mc[i][r], s);
        }
#pragma unroll
    for (int o = 1; o < 16; o <<= 1)
#pragma unroll
      for (int i = 0; i < 2; ++i)
#pragma unroll
        for (int r = 0; r < 4; ++r)
          mc[i][r] = fmaxf(mc[i][r], __shfl_xor(mc[i][r], o));

    // defer-max (T13): rescale only when chunk max grew past m + 8 (exact:
    // the stale-max factor cancels in O/l; P bounded by e^8, f32 l safe)
    bool need = false;
#pragma unroll
    for (int i = 0; i < 2; ++i)
#pragma unroll
      for (int r = 0; r < 4; ++r) need = need || (mc[i][r] > m_r[i][r] + 8.f);
    if (__any(need)) {
      float alpha[2][4];
#pragma unroll
      for (int i = 0; i < 2; ++i)
#pragma unroll
        for (int r = 0; r < 4; ++r) {
          float mn = fmaxf(m_r[i][r], mc[i][r]);
          alpha[i][r] = __expf(m_r[i][r] - mn);
          m_r[i][r] = mn;
          l_r[i][r] *= alpha[i][r];
        }
#pragma unroll
      for (int i = 0; i < 2; ++i)
#pragma unroll
        for (int j = 0; j < 8; ++j)
#pragma unroll
          for (int r = 0; r < 4; ++r) o_acc[i][j][r] *= alpha[i][r];
    }

    float ps[2][4];
#pragma unroll
    for (int i = 0; i < 2; ++i)
#pragma unroll
      for (int r = 0; r < 4; ++r) ps[i][r] = 0.f;
#pragma unroll
    for (int i = 0; i < 2; ++i)
#pragma unroll
      for (int j = 0; j < 4; ++j)
#pragma unroll
        for (int r = 0; r < 4; ++r) {
          float s = s_acc[i][j][r];
          float e = __expf(s - m_r[i][r]);
          e = (s == -1e30f) ? 0.f : e;
          s_acc[i][j][r] = e;
          ps[i][r] += e;
        }
#pragma unroll
    for (int o = 1; o < 16; o <<= 1)
#pragma unroll
      for (int i = 0; i < 2; ++i)
#pragma unroll
        for (int r = 0; r < 4; ++r) ps[i][r] += __shfl_xor(ps[i][r], o);
#pragma unroll
    for (int i = 0; i < 2; ++i)
#pragma unroll
      for (int r = 0; r < 4; ++r) l_r[i][r] += ps[i][r];

    // mid barrier: all waves' K-reads done -> P may overlay Ks[cur].
    // NO vmcnt drain: prefetch (into cur^1) keeps flying through PV.
    asm volatile("" ::: "memory");
    __builtin_amdgcn_s_barrier();
    asm volatile("" ::: "memory");

    u16* PsW = &Ks[cur][wave * 2048];
#pragma unroll
    for (int i = 0; i < 2; ++i)
#pragma unroll
      for (int r = 0; r < 4; ++r) {
        int xw = ((quad * 4 + r) & 7) << 3;
#pragma unroll
        for (int j = 0; j < 4; ++j)
          PsW[(i * 16 + quad * 4 + r) * 64 + ((j * 16 + l16) ^ xw)] = f2bf(s_acc[i][j][r]);
      }

#pragma unroll
    for (int kt = 0; kt < 2; ++kt) {
      frag8 pf[2], vf[8];
#pragma unroll
      for (int i = 0; i < 2; ++i)
        pf[i] = *(const frag8*)(PsW + (i * 16 + l16) * 64 + ((kt * 32 + quad * 8) ^ rsw));
#pragma unroll
      for (int j = 0; j < 8; ++j)
        vf[j] = *(const frag8*)(&Vs[cur][(j * 16 + l16) * 64 + ((kt * 32 + quad * 8) ^ rsw)]);
#pragma unroll
      for (int i = 0; i < 2; ++i)
#pragma unroll
        for (int j = 0; j < 8; ++j)
          o_acc[i][j] = __builtin_amdgcn_mfma_f32_16x16x32_bf16(pf[i], vf[j], o_acc[i][j], 0, 0, 0);
    }

    // end barrier: prefetch landed + all PV reads done before restage
    asm volatile("s_waitcnt vmcnt(0)" ::: "memory");
    __builtin_amdgcn_s_barrier();
    asm volatile("" ::: "memory");
    cur ^= 1;
  }

  float inv[2][4];
#pragma unroll
  for (int i = 0; i < 2; ++i)
#pragma unroll
    for (int r = 0; r < 4; ++r) inv[i][r] = 1.0f / l_r[i][r];
  u16* Ob = &Ks[0][0];  // 32KB contiguous: [128 row][128 u16]
#pragma unroll
  for (int i = 0; i < 2; ++i)
#pragma unroll
    for (int j = 0; j < 8; ++j)
#pragma unroll
      for (int r = 0; r < 4; ++r)
        Ob[(wave * 32 + i * 16 + quad * 4 + r) * 128 + j * 16 + l16] =
            f2bf(o_acc[i][j][r] * inv[i][r]);
  __syncthreads();
#pragma unroll
  for (int p = 0; p < 8; ++p) {
    int idx = p * 256 + tid;
    int row = idx >> 4, col = (idx & 15) * 8;
    *(frag8*)(O + (tok_q + row) * 2048 + h * 128 + col) = *(const frag8*)(Ob + row * 128 + col);
  }
}

__global__ void k_convert(const float4* __restrict__ x, ushort4* __restrict__ xb) {
  int i = blockIdx.x * 256 + threadIdx.x;
  float4 f = x[i];
  ushort4 o;
  o.x = f2bf(f.x); o.y = f2bf(f.y); o.z = f2bf(f.z); o.w = f2bf(f.w);
  xb[i] = o;
}

// W [K,N] fp32 -> W^T [N,K] bf16
__global__ void k_transpose(const float* __restrict__ W, u16* __restrict__ WT, int K, int N) {
  __shared__ float sh[32][33];
  int n0 = blockIdx.x * 32, k0 = blockIdx.y * 32;
  int tx = threadIdx.x, ty = threadIdx.y;  // (32, 8)
#pragma unroll
  for (int i = 0; i < 32; i += 8) sh[ty + i][tx] = W[(long)(k0 + ty + i) * N + n0 + tx];
  __syncthreads();
#pragma unroll
  for (int i = 0; i < 32; i += 8) WT[(long)(n0 + ty + i) * K + k0 + tx] = f2bf(sh[tx][ty + i]);
}

extern "C" void kernel_launch(void* const* d_in, const int* in_sizes, int n_in,
                              void* d_out, int out_size, void* d_ws, size_t ws_size,
                              hipStream_t stream) {
  const float* x  = (const float*)d_in[0];
  const float* Wq = (const float*)d_in[1];
  const float* Wk = (const float*)d_in[2];
  const float* Wv = (const float*)d_in[3];
  const float* Wo = (const float*)d_in[4];
  float* out = (float*)d_out;

  const long BT = 8192, D = 2048, NKV = 512;
  size_t off = 0;
  auto alloc = [&](size_t bytes) -> char* {
    off = (off + 255) & ~(size_t)255;
    char* p = (char*)d_ws + off;
    off += bytes;
    return p;
  };

  u16* xb  = (u16*)alloc((size_t)BT * D * 2);  // reused as attention output
  u16* WqT = (u16*)alloc((size_t)D * D * 2);
  u16* WkT = (u16*)alloc((size_t)NKV * D * 2);
  u16* WvT = (u16*)alloc((size_t)NKV * D * 2);
  u16* WoT = (u16*)alloc((size_t)D * D * 2);
  u16* qb  = (u16*)alloc((size_t)BT * D * 2);
  u16* kb  = (u16*)alloc((size_t)BT * NKV * 2);
  u16* vT  = (u16*)alloc((size_t)NKV * BT * 2);
  u16* Oa  = xb;

  k_convert<<<16384, 256, 0, stream>>>((const float4*)x, (ushort4*)xb);
  dim3 tb(32, 8);
  k_transpose<<<dim3(64, 64), tb, 0, stream>>>(Wq, WqT, 2048, 2048);
  k_transpose<<<dim3(16, 64), tb, 0, stream>>>(Wk, WkT, 2048, 512);
  k_transpose<<<dim3(16, 64), tb, 0, stream>>>(Wv, WvT, 2048, 512);
  k_transpose<<<dim3(64, 64), tb, 0, stream>>>(Wo, WoT, 2048, 2048);

  // Q projection pre-scales by 1/sqrt(HD)
  k_gemm256<u16><<<dim3(32, 8), 512, 0, stream>>>(xb, 2048, WqT, 2048, qb, 2048, 2048,
                                                  0.08838834764831845f);
  k_gemm_bf16 <<<dim3(64, 4),  256, 0, stream>>>(xb, 2048, WkT, 2048, kb, 512, 2048);
  k_gemm_bf16t<<<dim3(64, 4),  256, 0, stream>>>(xb, 2048, WvT, 2048, vT, 8192, 2048);

  k_attn<<<dim3(4, 8, 32), 256, 0, stream>>>(qb, kb, vT, Oa);

  k_gemm256<float><<<dim3(32, 8), 512, 0, stream>>>(Oa, 2048, WoT, 2048, out, 2048, 2048,
                                                    1.0f);
}